// Round 2
// baseline (259.098 us; speedup 1.0000x reference)
//
#include <hip/hip_runtime.h>
#include <math.h>

#define BB 4
#define SS 256
#define HID 512
#define NHD 8
#define DD 64

// ---------------- QKV projection GEMM: out = X @ W + b ----------------
// M=1024, N=512, K=512. Tile 64x64, BK=16, 256 threads, 4x4 per thread.
#define BM 64
#define BN 64
#define BK 16

__global__ __launch_bounds__(256) void qkv_gemm(
    const float* __restrict__ xq, const float* __restrict__ xk, const float* __restrict__ xv,
    const float* __restrict__ wq, const float* __restrict__ wk, const float* __restrict__ wv,
    const float* __restrict__ bq, const float* __restrict__ bk, const float* __restrict__ bv,
    float* __restrict__ oq, float* __restrict__ ok, float* __restrict__ ov)
{
    const int z = blockIdx.z;
    const float* X    = (z == 0) ? xq : (z == 1) ? xk : xv;
    const float* W    = (z == 0) ? wq : (z == 1) ? wk : wv;
    const float* bias = (z == 0) ? bq : (z == 1) ? bk : bv;
    float*       out  = (z == 0) ? oq : (z == 1) ? ok : ov;

    __shared__ float As[BK][BM];
    __shared__ float Bs[BK][BN];

    const int tid = threadIdx.x;
    const int bm = blockIdx.x * BM;
    const int bn = blockIdx.y * BN;
    const int tr = tid / 16;      // 0..15 row group
    const int tc = tid % 16;      // 0..15 col group

    float acc[4][4] = {};

    const int l = tid * 4;
    const int am = l / 16, ak = l % 16;   // A: 64 rows x 16 k
    const int bk_ = l / 64, bn_ = l % 64; // B: 16 k x 64 cols

    for (int k0 = 0; k0 < HID; k0 += BK) {
        float4 av = *(const float4*)&X[(size_t)(bm + am) * HID + k0 + ak];
        As[ak + 0][am] = av.x; As[ak + 1][am] = av.y;
        As[ak + 2][am] = av.z; As[ak + 3][am] = av.w;
        float4 bv4 = *(const float4*)&W[(size_t)(k0 + bk_) * HID + bn + bn_];
        Bs[bk_][bn_ + 0] = bv4.x; Bs[bk_][bn_ + 1] = bv4.y;
        Bs[bk_][bn_ + 2] = bv4.z; Bs[bk_][bn_ + 3] = bv4.w;
        __syncthreads();
        #pragma unroll
        for (int kk = 0; kk < BK; ++kk) {
            float a[4], b[4];
            #pragma unroll
            for (int i = 0; i < 4; ++i) a[i] = As[kk][tr * 4 + i];
            #pragma unroll
            for (int j = 0; j < 4; ++j) b[j] = Bs[kk][tc * 4 + j];
            #pragma unroll
            for (int i = 0; i < 4; ++i)
                #pragma unroll
                for (int j = 0; j < 4; ++j)
                    acc[i][j] += a[i] * b[j];
        }
        __syncthreads();
    }

    #pragma unroll
    for (int i = 0; i < 4; ++i) {
        const int row = bm + tr * 4 + i;
        #pragma unroll
        for (int j = 0; j < 4; ++j) {
            const int col = bn + tc * 4 + j;
            out[(size_t)row * HID + col] = acc[i][j] + bias[col];
        }
    }
}

// ---------------- cumulative histogram over t for each column j ----------------
// cnt[b,i,j,e] = #{t<=i : edge_type[b,t,j]==e}, packed as 8 x u16 (uint4 per (b,i,j))
__global__ __launch_bounds__(256) void cnt_kernel(
    const int* __restrict__ edge, uint4* __restrict__ cnt)
{
    const int idx = blockIdx.x * blockDim.x + threadIdx.x; // b*S + j
    const int b = idx / SS, j = idx % SS;
    unsigned int h0 = 0, h1 = 0, h2 = 0, h3 = 0, h4 = 0, h5 = 0, h6 = 0, h7 = 0;
    for (int i = 0; i < SS; ++i) {
        const int e = edge[((size_t)(b * SS + i)) * SS + j];
        h0 += (e == 0); h1 += (e == 1); h2 += (e == 2); h3 += (e == 3);
        h4 += (e == 4); h5 += (e == 5); h6 += (e == 6); h7 += (e == 7);
        cnt[((size_t)(b * SS + i)) * SS + j] =
            make_uint4(h0 | (h1 << 16), h2 | (h3 << 16), h4 | (h5 << 16), h6 | (h7 << 16));
    }
}

// ---------------- qrow (in place over Q0) and qre ----------------
// block per (b,i), 512 threads: wave = head h, lane = d
__global__ __launch_bounds__(512) void qrow_qre(
    float* __restrict__ Q,                 // [B,S,HID] in/out
    const uint4* __restrict__ cnt,         // [B,S,S] packed
    const float* __restrict__ rel,         // [8,HID]
    float* __restrict__ qre)               // [B,NH,S,8]
{
    const int b = blockIdx.x / SS, i = blockIdx.x % SS;
    const int col = threadIdx.x;           // h*64+d
    const int h = col >> 6, d = col & 63;

    const uint4 cv = cnt[((size_t)(b * SS + i)) * SS + i];
    float c[8];
    c[0] = (float)(cv.x & 0xffff); c[1] = (float)(cv.x >> 16);
    c[2] = (float)(cv.y & 0xffff); c[3] = (float)(cv.y >> 16);
    c[4] = (float)(cv.z & 0xffff); c[5] = (float)(cv.z >> 16);
    c[6] = (float)(cv.w & 0xffff); c[7] = (float)(cv.w >> 16);

    float q = Q[((size_t)(b * SS + i)) * HID + col];
    #pragma unroll
    for (int e = 0; e < 8; ++e) q += c[e] * rel[e * HID + col];
    Q[((size_t)(b * SS + i)) * HID + col] = q;

    // qre[b,h,i,e] = sum_d q * rel[e, h*64+d]  (reduce within the wave)
    #pragma unroll
    for (int e = 0; e < 8; ++e) {
        float v = q * rel[e * HID + col];
        #pragma unroll
        for (int off = 32; off > 0; off >>= 1) v += __shfl_xor(v, off);
        if (d == 0) qre[(((size_t)(b * NHD + h)) * SS + i) * 8 + e] = v;
    }
}

// ---------------- attention: one block per (b,h,i), 256 threads ----------------
__global__ __launch_bounds__(256) void attn_kernel(
    const float* __restrict__ qrow,   // [B,S,HID]
    const float* __restrict__ K0,     // [B,S,HID]
    const float* __restrict__ V0,     // [B,S,HID]
    const float* __restrict__ qre,    // [B,NH,S,8]
    const uint4* __restrict__ cnt,    // [B,S,S]
    const int* __restrict__ mask,     // [B,S,S]
    float* __restrict__ out)          // [B,S,HID]
{
    const int x = blockIdx.x;
    const int i = x % SS;
    const int h = (x / SS) % NHD;
    const int b = x / (SS * NHD);
    const int j = threadIdx.x;
    const int wave = threadIdx.x >> 6, lane = threadIdx.x & 63;

    __shared__ float qs[DD];
    __shared__ float probs[256];
    __shared__ float wred[4];
    __shared__ float wsum[4];
    __shared__ float part[4][DD];

    if (threadIdx.x < DD)
        qs[threadIdx.x] = qrow[((size_t)(b * SS + i)) * HID + h * DD + threadIdx.x];
    float qr[8];
    {
        const float* qrp = &qre[(((size_t)(b * NHD + h)) * SS + i) * 8];
        #pragma unroll
        for (int e = 0; e < 8; ++e) qr[e] = qrp[e];
    }
    __syncthreads();

    // score for column j
    const float* Krow = &K0[((size_t)(b * SS + j)) * HID + h * DD];
    float s = 0.f;
    #pragma unroll
    for (int d4 = 0; d4 < DD; d4 += 4) {
        float4 kv = *(const float4*)&Krow[d4];
        s += qs[d4] * kv.x + qs[d4 + 1] * kv.y + qs[d4 + 2] * kv.z + qs[d4 + 3] * kv.w;
    }
    {
        const uint4 cv = cnt[((size_t)(b * SS + i)) * SS + j];
        s += qr[0] * (float)(cv.x & 0xffff) + qr[1] * (float)(cv.x >> 16)
           + qr[2] * (float)(cv.y & 0xffff) + qr[3] * (float)(cv.y >> 16)
           + qr[4] * (float)(cv.z & 0xffff) + qr[5] * (float)(cv.z >> 16)
           + qr[6] * (float)(cv.w & 0xffff) + qr[7] * (float)(cv.w >> 16);
    }
    s *= 0.125f;  // 1/sqrt(64)
    const int m = mask[((size_t)(b * SS + i)) * SS + j];
    s = m ? s : -1e9f;

    // block softmax (max)
    float mx = s;
    #pragma unroll
    for (int off = 32; off > 0; off >>= 1) mx = fmaxf(mx, __shfl_xor(mx, off));
    if (lane == 0) wred[wave] = mx;
    __syncthreads();
    mx = fmaxf(fmaxf(wred[0], wred[1]), fmaxf(wred[2], wred[3]));

    float p = __expf(s - mx);
    float sm = p;
    #pragma unroll
    for (int off = 32; off > 0; off >>= 1) sm += __shfl_xor(sm, off);
    if (lane == 0) wsum[wave] = sm;
    __syncthreads();
    const float tot = wsum[0] + wsum[1] + wsum[2] + wsum[3];
    p /= tot;
    probs[j] = p;
    __syncthreads();

    // PV: wave w sums j in [w*64, w*64+64), lane = d
    float acc = 0.f;
    const float* Vbase = &V0[((size_t)(b * SS + wave * 64)) * HID + h * DD + lane];
    #pragma unroll 8
    for (int jj = 0; jj < 64; ++jj)
        acc += probs[wave * 64 + jj] * Vbase[(size_t)jj * HID];
    part[wave][lane] = acc;
    __syncthreads();
    if (threadIdx.x < DD) {
        const float r = part[0][threadIdx.x] + part[1][threadIdx.x]
                      + part[2][threadIdx.x] + part[3][threadIdx.x];
        out[((size_t)(b * SS + i)) * HID + h * DD + threadIdx.x] = r;
    }
}

extern "C" void kernel_launch(void* const* d_in, const int* in_sizes, int n_in,
                              void* d_out, int out_size, void* d_ws, size_t ws_size,
                              hipStream_t stream) {
    const float* q_hs = (const float*)d_in[0];
    const float* k_hs = (const float*)d_in[1];
    const float* v_hs = (const float*)d_in[2];
    const float* Wq   = (const float*)d_in[3];
    const float* bq   = (const float*)d_in[4];
    const float* Wk   = (const float*)d_in[5];
    const float* bk   = (const float*)d_in[6];
    const float* Wv   = (const float*)d_in[7];
    const float* bv   = (const float*)d_in[8];
    const float* rel  = (const float*)d_in[9];
    const int* edge   = (const int*)d_in[10];
    const int* mask   = (const int*)d_in[11];
    float* out = (float*)d_out;

    char* ws = (char*)d_ws;
    float* Q   = (float*)(ws);                       // 2 MB  [B,S,HID] -> becomes qrow
    float* K0  = (float*)(ws + (2u << 20));          // 2 MB
    float* V0  = (float*)(ws + (4u << 20));          // 2 MB
    float* qre = (float*)(ws + (6u << 20));          // 256 KB [B,NH,S,8]
    uint4* cnt = (uint4*)(ws + (7u << 20));          // 4 MB  [B,S,S] packed u16x8

    // 1) QKV projections
    {
        dim3 grid(1024 / BM, HID / BN, 3);
        qkv_gemm<<<grid, 256, 0, stream>>>(q_hs, k_hs, v_hs, Wq, Wk, Wv,
                                           bq, bk, bv, Q, K0, V0);
    }
    // 2) cumulative histogram
    cnt_kernel<<<dim3(BB * SS / 256), 256, 0, stream>>>(edge, cnt);
    // 3) qrow (in place) + qre
    qrow_qre<<<dim3(BB * SS), 512, 0, stream>>>(Q, cnt, rel, qre);
    // 4) attention
    attn_kernel<<<dim3(BB * NHD * SS), 256, 0, stream>>>(Q, K0, V0, qre, cnt, mask, out);
}

// Round 4
// 151.073 us; speedup vs baseline: 1.7151x; 1.7151x over previous
//
#include <hip/hip_runtime.h>
#include <math.h>

#define BB 4
#define SS 256
#define HID 512
#define NHD 8
#define DD 64
#define IT 16   // query rows per attn block

// ---------------- QKV projection GEMM: out = X @ W + b ----------------
#define BM 64
#define BN 64
#define BK 16

__global__ __launch_bounds__(256) void qkv_gemm(
    const float* __restrict__ xq, const float* __restrict__ xk, const float* __restrict__ xv,
    const float* __restrict__ wq, const float* __restrict__ wk, const float* __restrict__ wv,
    const float* __restrict__ bq, const float* __restrict__ bk, const float* __restrict__ bv,
    float* __restrict__ oq, float* __restrict__ ok, float* __restrict__ ov)
{
    const int z = blockIdx.z;
    const float* X    = (z == 0) ? xq : (z == 1) ? xk : xv;
    const float* W    = (z == 0) ? wq : (z == 1) ? wk : wv;
    const float* bias = (z == 0) ? bq : (z == 1) ? bk : bv;
    float*       out  = (z == 0) ? oq : (z == 1) ? ok : ov;

    __shared__ float As[BK][BM];
    __shared__ float Bs[BK][BN];

    const int tid = threadIdx.x;
    const int bm = blockIdx.x * BM;
    const int bn = blockIdx.y * BN;
    const int tr = tid / 16;
    const int tc = tid % 16;

    float acc[4][4] = {};

    const int l = tid * 4;
    const int am = l / 16, ak = l % 16;
    const int bk_ = l / 64, bn_ = l % 64;

    for (int k0 = 0; k0 < HID; k0 += BK) {
        float4 av = *(const float4*)&X[(size_t)(bm + am) * HID + k0 + ak];
        As[ak + 0][am] = av.x; As[ak + 1][am] = av.y;
        As[ak + 2][am] = av.z; As[ak + 3][am] = av.w;
        float4 bv4 = *(const float4*)&W[(size_t)(k0 + bk_) * HID + bn + bn_];
        Bs[bk_][bn_ + 0] = bv4.x; Bs[bk_][bn_ + 1] = bv4.y;
        Bs[bk_][bn_ + 2] = bv4.z; Bs[bk_][bn_ + 3] = bv4.w;
        __syncthreads();
        #pragma unroll
        for (int kk = 0; kk < BK; ++kk) {
            float a[4], b[4];
            #pragma unroll
            for (int i = 0; i < 4; ++i) a[i] = As[kk][tr * 4 + i];
            #pragma unroll
            for (int j = 0; j < 4; ++j) b[j] = Bs[kk][tc * 4 + j];
            #pragma unroll
            for (int i = 0; i < 4; ++i)
                #pragma unroll
                for (int j = 0; j < 4; ++j)
                    acc[i][j] += a[i] * b[j];
        }
        __syncthreads();
    }

    #pragma unroll
    for (int i = 0; i < 4; ++i) {
        const int row = bm + tr * 4 + i;
        #pragma unroll
        for (int j = 0; j < 4; ++j) {
            const int col = bn + tc * 4 + j;
            out[(size_t)row * HID + col] = acc[i][j] + bias[col];
        }
    }
}

// ---------------- parallel cumulative histogram (wave scan) ----------------
// one wave per column (b,j); lane l owns rows l*4..l*4+3; packed 8 x u16 in uint4
__global__ __launch_bounds__(256) void cnt_kernel(
    const int* __restrict__ edge, uint4* __restrict__ cnt)
{
    const int wave = threadIdx.x >> 6, lane = threadIdx.x & 63;
    const int col = blockIdx.x * 4 + wave;           // 0 .. B*S-1
    const int b = col / SS, j = col % SS;

    uint4 run = make_uint4(0, 0, 0, 0);
    uint4 c[4];
    #pragma unroll
    for (int r = 0; r < 4; ++r) {
        const int e = edge[((size_t)(b * SS + lane * 4 + r)) * SS + j];
        const unsigned inc = 1u << ((e & 1) * 16);
        const int comp = e >> 1;
        run.x += (comp == 0) ? inc : 0u;
        run.y += (comp == 1) ? inc : 0u;
        run.z += (comp == 2) ? inc : 0u;
        run.w += (comp == 3) ? inc : 0u;
        c[r] = run;
    }
    // inclusive wave scan of run
    uint4 tot = run;
    #pragma unroll
    for (int off = 1; off < 64; off <<= 1) {
        uint4 t;
        t.x = __shfl_up((int)tot.x, off);
        t.y = __shfl_up((int)tot.y, off);
        t.z = __shfl_up((int)tot.z, off);
        t.w = __shfl_up((int)tot.w, off);
        if (lane >= off) { tot.x += t.x; tot.y += t.y; tot.z += t.z; tot.w += t.w; }
    }
    const uint4 excl = make_uint4(tot.x - run.x, tot.y - run.y, tot.z - run.z, tot.w - run.w);
    #pragma unroll
    for (int r = 0; r < 4; ++r) {
        uint4 o = make_uint4(excl.x + c[r].x, excl.y + c[r].y, excl.z + c[r].z, excl.w + c[r].w);
        cnt[((size_t)(b * SS + lane * 4 + r)) * SS + j] = o;
    }
}

// ---------------- qrow (in place over Q0) and qre ----------------
__global__ __launch_bounds__(512) void qrow_qre(
    float* __restrict__ Q,
    const uint4* __restrict__ cnt,
    const float* __restrict__ rel,
    float* __restrict__ qre)
{
    const int b = blockIdx.x / SS, i = blockIdx.x % SS;
    const int col = threadIdx.x;
    const int h = col >> 6, d = col & 63;

    const uint4 cv = cnt[((size_t)(b * SS + i)) * SS + i];
    float c[8];
    c[0] = (float)(cv.x & 0xffff); c[1] = (float)(cv.x >> 16);
    c[2] = (float)(cv.y & 0xffff); c[3] = (float)(cv.y >> 16);
    c[4] = (float)(cv.z & 0xffff); c[5] = (float)(cv.z >> 16);
    c[6] = (float)(cv.w & 0xffff); c[7] = (float)(cv.w >> 16);

    float q = Q[((size_t)(b * SS + i)) * HID + col];
    #pragma unroll
    for (int e = 0; e < 8; ++e) q += c[e] * rel[e * HID + col];
    Q[((size_t)(b * SS + i)) * HID + col] = q;

    #pragma unroll
    for (int e = 0; e < 8; ++e) {
        float v = q * rel[e * HID + col];
        #pragma unroll
        for (int off = 32; off > 0; off >>= 1) v += __shfl_xor(v, off);
        if (d == 0) qre[(((size_t)(b * NHD + h)) * SS + i) * 8 + e] = v;
    }
}

// ---------------- attention v2: block = (b, h, 16-row i-tile), 256 threads ----------------
__global__ __launch_bounds__(256) void attn_kernel(
    const float* __restrict__ qrow,   // [B,S,HID]
    const float* __restrict__ K0,     // [B,S,HID]
    const float* __restrict__ V0,     // [B,S,HID]
    const float* __restrict__ qre,    // [B,NH,S,8]
    const uint4* __restrict__ cnt,    // [B,S,S]
    const int* __restrict__ mask,     // [B,S,S]
    float* __restrict__ out)          // [B,S,HID]
{
    const int x = blockIdx.x;
    const int it = x & 15;
    const int h  = (x >> 4) & 7;
    const int b  = x >> 7;
    const int i0 = it * IT;
    const int tid = threadIdx.x;
    const int wave = tid >> 6, lane = tid & 63;

    __shared__ float qs[IT][DD];          // 4 KB
    __shared__ float qre_s[IT][8];        // 512 B
    __shared__ float s_t[SS][IT + 1];     // 17.4 KB, +1 pad -> conflict-free col reads
    __shared__ float vtile[64][DD];       // 16 KB

    // phase 1: stage q rows + qre
    {
        const int i = tid >> 4, d4 = tid & 15;
        *(float4*)&qs[i][d4 * 4] =
            *(const float4*)&qrow[((size_t)(b * SS + i0 + i)) * HID + h * DD + d4 * 4];
        if (tid < IT * 8)
            qre_s[tid >> 3][tid & 7] =
                qre[(((size_t)(b * NHD + h)) * SS + i0 + (tid >> 3)) * 8 + (tid & 7)];
    }
    __syncthreads();

    // phase 2: scores, thread = column j, K row held in registers
    {
        const int j = tid;
        float4 kreg[16];
        #pragma unroll
        for (int d4 = 0; d4 < 16; ++d4)
            kreg[d4] = *(const float4*)&K0[((size_t)(b * SS + j)) * HID + h * DD + d4 * 4];

        #pragma unroll
        for (int i = 0; i < IT; ++i) {
            float s = 0.f;
            #pragma unroll
            for (int d4 = 0; d4 < 16; ++d4) {
                const float4 q = *(const float4*)&qs[i][d4 * 4];
                s += q.x * kreg[d4].x + q.y * kreg[d4].y + q.z * kreg[d4].z + q.w * kreg[d4].w;
            }
            const uint4 cv = cnt[((size_t)(b * SS + i0 + i)) * SS + j];
            s += qre_s[i][0] * (float)(cv.x & 0xffff) + qre_s[i][1] * (float)(cv.x >> 16)
               + qre_s[i][2] * (float)(cv.y & 0xffff) + qre_s[i][3] * (float)(cv.y >> 16)
               + qre_s[i][4] * (float)(cv.z & 0xffff) + qre_s[i][5] * (float)(cv.z >> 16)
               + qre_s[i][6] * (float)(cv.w & 0xffff) + qre_s[i][7] * (float)(cv.w >> 16);
            s *= 0.125f;
            const int m = mask[((size_t)(b * SS + i0 + i)) * SS + j];
            s_t[j][i] = m ? s : -1e9f;
        }
    }
    __syncthreads();

    // phase 3: softmax per row; wave w handles rows w*4 .. w*4+3
    #pragma unroll
    for (int rr = 0; rr < 4; ++rr) {
        const int i = wave * 4 + rr;
        float v0 = s_t[lane][i], v1 = s_t[lane + 64][i],
              v2 = s_t[lane + 128][i], v3 = s_t[lane + 192][i];
        float mx = fmaxf(fmaxf(v0, v1), fmaxf(v2, v3));
        #pragma unroll
        for (int off = 32; off > 0; off >>= 1) mx = fmaxf(mx, __shfl_xor(mx, off));
        float e0 = __expf(v0 - mx), e1 = __expf(v1 - mx),
              e2 = __expf(v2 - mx), e3 = __expf(v3 - mx);
        float sm = e0 + e1 + e2 + e3;
        #pragma unroll
        for (int off = 32; off > 0; off >>= 1) sm += __shfl_xor(sm, off);
        const float inv = 1.f / sm;
        s_t[lane][i] = e0 * inv;
        s_t[lane + 64][i] = e1 * inv;
        s_t[lane + 128][i] = e2 * inv;
        s_t[lane + 192][i] = e3 * inv;
    }
    __syncthreads();

    // phase 4: PV; thread = (i-quad, d): d = tid&63, rows i4*4..i4*4+3
    {
        const int d = tid & 63, i4 = tid >> 6;
        float acc0 = 0.f, acc1 = 0.f, acc2 = 0.f, acc3 = 0.f;
        for (int jt = 0; jt < 4; ++jt) {
            // stage V tile [64][64]
            {
                const int jr = tid >> 2, seg = tid & 3;
                const float* src = &V0[((size_t)(b * SS + jt * 64 + jr)) * HID + h * DD + seg * 16];
                #pragma unroll
                for (int q = 0; q < 4; ++q)
                    *(float4*)&vtile[jr][seg * 16 + q * 4] = *(const float4*)&src[q * 4];
            }
            __syncthreads();
            #pragma unroll 16
            for (int jj = 0; jj < 64; ++jj) {
                const int j = jt * 64 + jj;
                const float v = vtile[jj][d];
                acc0 += s_t[j][i4 * 4 + 0] * v;
                acc1 += s_t[j][i4 * 4 + 1] * v;
                acc2 += s_t[j][i4 * 4 + 2] * v;
                acc3 += s_t[j][i4 * 4 + 3] * v;
            }
            __syncthreads();
        }
        out[((size_t)(b * SS + i0 + i4 * 4 + 0)) * HID + h * DD + d] = acc0;
        out[((size_t)(b * SS + i0 + i4 * 4 + 1)) * HID + h * DD + d] = acc1;
        out[((size_t)(b * SS + i0 + i4 * 4 + 2)) * HID + h * DD + d] = acc2;
        out[((size_t)(b * SS + i0 + i4 * 4 + 3)) * HID + h * DD + d] = acc3;
    }
}

extern "C" void kernel_launch(void* const* d_in, const int* in_sizes, int n_in,
                              void* d_out, int out_size, void* d_ws, size_t ws_size,
                              hipStream_t stream) {
    const float* q_hs = (const float*)d_in[0];
    const float* k_hs = (const float*)d_in[1];
    const float* v_hs = (const float*)d_in[2];
    const float* Wq   = (const float*)d_in[3];
    const float* bq   = (const float*)d_in[4];
    const float* Wk   = (const float*)d_in[5];
    const float* bk   = (const float*)d_in[6];
    const float* Wv   = (const float*)d_in[7];
    const float* bv   = (const float*)d_in[8];
    const float* rel  = (const float*)d_in[9];
    const int* edge   = (const int*)d_in[10];
    const int* mask   = (const int*)d_in[11];
    float* out = (float*)d_out;

    char* ws = (char*)d_ws;
    float* Q   = (float*)(ws);                       // 2 MB  [B,S,HID] -> becomes qrow
    float* K0  = (float*)(ws + (2u << 20));          // 2 MB
    float* V0  = (float*)(ws + (4u << 20));          // 2 MB
    float* qre = (float*)(ws + (6u << 20));          // 256 KB [B,NH,S,8]
    uint4* cnt = (uint4*)(ws + (7u << 20));          // 4 MB  [B,S,S] packed u16x8

    {
        dim3 grid(1024 / BM, HID / BN, 3);
        qkv_gemm<<<grid, 256, 0, stream>>>(q_hs, k_hs, v_hs, Wq, Wk, Wv,
                                           bq, bk, bv, Q, K0, V0);
    }
    cnt_kernel<<<dim3(BB * SS / 4), 256, 0, stream>>>(edge, cnt);
    qrow_qre<<<dim3(BB * SS), 512, 0, stream>>>(Q, cnt, rel, qre);
    attn_kernel<<<dim3(BB * NHD * (SS / IT)), 256, 0, stream>>>(Q, K0, V0, qre, cnt, mask, out);
}

// Round 5
// 139.447 us; speedup vs baseline: 1.8580x; 1.0834x over previous
//
#include <hip/hip_runtime.h>
#include <math.h>

#define BB 4
#define SS 256
#define HID 512
#define NHD 8
#define DD 64
#define IT 16

// ---------------- QKV projection GEMM: out = X @ W + b ----------------
// 64x64 tile, split-K in-block: waves 0-3 k:[0,256), waves 4-7 k:[256,512).
__global__ __launch_bounds__(512) void qkv_gemm(
    const float* __restrict__ xq, const float* __restrict__ xk, const float* __restrict__ xv,
    const float* __restrict__ wq, const float* __restrict__ wk, const float* __restrict__ wv,
    const float* __restrict__ bq, const float* __restrict__ bk, const float* __restrict__ bv,
    float* __restrict__ oq, float* __restrict__ ok, float* __restrict__ ov)
{
    const int z = blockIdx.z;
    const float* X    = (z == 0) ? xq : (z == 1) ? xk : xv;
    const float* W    = (z == 0) ? wq : (z == 1) ? wk : wv;
    const float* bias = (z == 0) ? bq : (z == 1) ? bk : bv;
    float*       out  = (z == 0) ? oq : (z == 1) ? ok : ov;

    __shared__ float As[2][16][64];
    __shared__ float Bs[2][16][64];
    __shared__ float cbuf[64][65];

    const int t = threadIdx.x;
    const int khalf = t >> 8;
    const int tid = t & 255;
    const int bm = blockIdx.x * 64;
    const int bn = blockIdx.y * 64;
    const int tr = tid >> 4;
    const int tc = tid & 15;

    float acc[4][4] = {};

    const int l = tid * 4;
    const int am = l >> 4, ak = l & 15;
    const int bk_ = l >> 6, bn_ = l & 63;
    const int kbase = khalf * 256;

    for (int k0 = kbase; k0 < kbase + 256; k0 += 16) {
        float4 av = *(const float4*)&X[(size_t)(bm + am) * HID + k0 + ak];
        As[khalf][ak + 0][am] = av.x; As[khalf][ak + 1][am] = av.y;
        As[khalf][ak + 2][am] = av.z; As[khalf][ak + 3][am] = av.w;
        float4 bv4 = *(const float4*)&W[(size_t)(k0 + bk_) * HID + bn + bn_];
        Bs[khalf][bk_][bn_ + 0] = bv4.x; Bs[khalf][bk_][bn_ + 1] = bv4.y;
        Bs[khalf][bk_][bn_ + 2] = bv4.z; Bs[khalf][bk_][bn_ + 3] = bv4.w;
        __syncthreads();
        #pragma unroll
        for (int kk = 0; kk < 16; ++kk) {
            float a[4], b[4];
            #pragma unroll
            for (int i = 0; i < 4; ++i) a[i] = As[khalf][kk][tr * 4 + i];
            #pragma unroll
            for (int j = 0; j < 4; ++j) b[j] = Bs[khalf][kk][tc * 4 + j];
            #pragma unroll
            for (int i = 0; i < 4; ++i)
                #pragma unroll
                for (int j = 0; j < 4; ++j)
                    acc[i][j] += a[i] * b[j];
        }
        __syncthreads();
    }

    if (khalf == 1) {
        #pragma unroll
        for (int i = 0; i < 4; ++i)
            #pragma unroll
            for (int j = 0; j < 4; ++j)
                cbuf[tr * 4 + i][tc * 4 + j] = acc[i][j];
    }
    __syncthreads();
    if (khalf == 0) {
        #pragma unroll
        for (int i = 0; i < 4; ++i) {
            const int row = bm + tr * 4 + i;
            float4 o;
            o.x = acc[i][0] + cbuf[tr * 4 + i][tc * 4 + 0] + bias[bn + tc * 4 + 0];
            o.y = acc[i][1] + cbuf[tr * 4 + i][tc * 4 + 1] + bias[bn + tc * 4 + 1];
            o.z = acc[i][2] + cbuf[tr * 4 + i][tc * 4 + 2] + bias[bn + tc * 4 + 2];
            o.w = acc[i][3] + cbuf[tr * 4 + i][tc * 4 + 3] + bias[bn + tc * 4 + 3];
            *(float4*)&out[(size_t)row * HID + bn + tc * 4] = o;
        }
    }
}

// ---------------- parallel cumulative histogram (wave scan) ----------------
__global__ __launch_bounds__(256) void cnt_kernel(
    const int* __restrict__ edge, uint4* __restrict__ cnt)
{
    const int wave = threadIdx.x >> 6, lane = threadIdx.x & 63;
    const int col = blockIdx.x * 4 + wave;
    const int b = col / SS, j = col % SS;

    uint4 run = make_uint4(0, 0, 0, 0);
    uint4 c[4];
    #pragma unroll
    for (int r = 0; r < 4; ++r) {
        const int e = edge[((size_t)(b * SS + lane * 4 + r)) * SS + j];
        const unsigned inc = 1u << ((e & 1) * 16);
        const int comp = e >> 1;
        run.x += (comp == 0) ? inc : 0u;
        run.y += (comp == 1) ? inc : 0u;
        run.z += (comp == 2) ? inc : 0u;
        run.w += (comp == 3) ? inc : 0u;
        c[r] = run;
    }
    uint4 tot = run;
    #pragma unroll
    for (int off = 1; off < 64; off <<= 1) {
        uint4 t;
        t.x = __shfl_up((int)tot.x, off);
        t.y = __shfl_up((int)tot.y, off);
        t.z = __shfl_up((int)tot.z, off);
        t.w = __shfl_up((int)tot.w, off);
        if (lane >= off) { tot.x += t.x; tot.y += t.y; tot.z += t.z; tot.w += t.w; }
    }
    const uint4 excl = make_uint4(tot.x - run.x, tot.y - run.y, tot.z - run.z, tot.w - run.w);
    #pragma unroll
    for (int r = 0; r < 4; ++r) {
        uint4 o = make_uint4(excl.x + c[r].x, excl.y + c[r].y, excl.z + c[r].z, excl.w + c[r].w);
        cnt[((size_t)(b * SS + lane * 4 + r)) * SS + j] = o;
    }
}

// ---------------- fused attention (qrow+qre computed in-block) ----------------
// block = (b, h, 16-row i-tile), 256 threads
__global__ __launch_bounds__(256) void attn_fused(
    const float* __restrict__ Q0,     // [B,S,HID] raw projection
    const float* __restrict__ K0,
    const float* __restrict__ V0,
    const float* __restrict__ rel,    // [8,HID]
    const uint4* __restrict__ cnt,    // [B,S,S] packed u16x8
    const int* __restrict__ mask,     // [B,S,S]
    float* __restrict__ out)          // [B,S,HID]
{
    const int x = blockIdx.x;
    const int it = x & 15;
    const int h  = (x >> 4) & 7;
    const int b  = x >> 7;
    const int i0 = it * IT;
    const int t = threadIdx.x;

    __shared__ float qst[DD][20];      // qrow transposed [d][i], stride 20 (80B, b128-aligned)
    __shared__ float qre_s[IT][8];
    __shared__ float s_t[SS][20];      // scores/probs [j][i], stride 20
    __shared__ float kv[DD][68];       // K: [d][j'] transposed; V: [j'][d] natural

    // ---- phase 0a: qrow = Q0 + sum_e cnt_diag[e]*rel[e] -> qst (transposed) ----
    {
        const int d4 = t >> 4, i = t & 15;
        const float4 q4 = *(const float4*)&Q0[((size_t)(b * SS + i0 + i)) * HID + h * DD + d4 * 4];
        const uint4 cv = cnt[((size_t)(b * SS + i0 + i)) * SS + (i0 + i)];
        float c[8];
        c[0] = (float)(cv.x & 0xffff); c[1] = (float)(cv.x >> 16);
        c[2] = (float)(cv.y & 0xffff); c[3] = (float)(cv.y >> 16);
        c[4] = (float)(cv.z & 0xffff); c[5] = (float)(cv.z >> 16);
        c[6] = (float)(cv.w & 0xffff); c[7] = (float)(cv.w >> 16);
        float o0 = q4.x, o1 = q4.y, o2 = q4.z, o3 = q4.w;
        #pragma unroll
        for (int e = 0; e < 8; ++e) {
            const float4 r4 = *(const float4*)&rel[e * HID + h * DD + d4 * 4];
            o0 += c[e] * r4.x; o1 += c[e] * r4.y; o2 += c[e] * r4.z; o3 += c[e] * r4.w;
        }
        qst[d4 * 4 + 0][i] = o0;
        qst[d4 * 4 + 1][i] = o1;
        qst[d4 * 4 + 2][i] = o2;
        qst[d4 * 4 + 3][i] = o3;
    }
    __syncthreads();

    // ---- phase 0b: qre[i][e] = dot(qrow[i], rel[e, hslice]) ----
    if (t < 128) {
        const int i = t >> 3, e = t & 7;
        const float* rp = &rel[e * HID + h * DD];
        float s = 0.f;
        #pragma unroll 8
        for (int d = 0; d < DD; ++d) s += qst[d][i] * rp[d];
        qre_s[i][e] = s;
    }
    __syncthreads();

    // ---- phase 2: scores S[16][256] via outer-product; j in 4 tiles of 64 ----
    const int iq = t >> 6;             // wave = i-quad
    const int dsp = (t >> 4) & 3;      // d-split
    const int jq = t & 15;             // j-quad within tile
    for (int jt = 0; jt < 4; ++jt) {
        // stage K tile transposed: kv[d][j']
        {
            const int jr = t >> 2, seg = t & 3;
            const float* src = &K0[((size_t)(b * SS + jt * 64 + jr)) * HID + h * DD + seg * 16];
            const float4 a0 = *(const float4*)&src[0];
            const float4 a1 = *(const float4*)&src[4];
            const float4 a2 = *(const float4*)&src[8];
            const float4 a3 = *(const float4*)&src[12];
            kv[seg * 16 +  0][jr] = a0.x; kv[seg * 16 +  1][jr] = a0.y;
            kv[seg * 16 +  2][jr] = a0.z; kv[seg * 16 +  3][jr] = a0.w;
            kv[seg * 16 +  4][jr] = a1.x; kv[seg * 16 +  5][jr] = a1.y;
            kv[seg * 16 +  6][jr] = a1.z; kv[seg * 16 +  7][jr] = a1.w;
            kv[seg * 16 +  8][jr] = a2.x; kv[seg * 16 +  9][jr] = a2.y;
            kv[seg * 16 + 10][jr] = a2.z; kv[seg * 16 + 11][jr] = a2.w;
            kv[seg * 16 + 12][jr] = a3.x; kv[seg * 16 + 13][jr] = a3.y;
            kv[seg * 16 + 14][jr] = a3.z; kv[seg * 16 + 15][jr] = a3.w;
        }
        __syncthreads();

        float part[4][4] = {};
        #pragma unroll
        for (int dd = 0; dd < 16; ++dd) {
            const int d = dsp * 16 + dd;
            const float4 q4 = *(const float4*)&qst[d][iq * 4];
            const float4 k4 = *(const float4*)&kv[d][jq * 4];
            part[0][0] += q4.x * k4.x; part[0][1] += q4.x * k4.y;
            part[0][2] += q4.x * k4.z; part[0][3] += q4.x * k4.w;
            part[1][0] += q4.y * k4.x; part[1][1] += q4.y * k4.y;
            part[1][2] += q4.y * k4.z; part[1][3] += q4.y * k4.w;
            part[2][0] += q4.z * k4.x; part[2][1] += q4.z * k4.y;
            part[2][2] += q4.z * k4.z; part[2][3] += q4.z * k4.w;
            part[3][0] += q4.w * k4.x; part[3][1] += q4.w * k4.y;
            part[3][2] += q4.w * k4.z; part[3][3] += q4.w * k4.w;
        }
        // reduce over dsp (lane bits 4,5)
        #pragma unroll
        for (int r = 0; r < 4; ++r)
            #pragma unroll
            for (int c = 0; c < 4; ++c) {
                float v = part[r][c];
                v += __shfl_xor(v, 16);
                v += __shfl_xor(v, 32);
                part[r][c] = v;
            }
        // this thread finalizes row i = iq*4 + dsp, cols jbase..+3
        float sv[4];
        #pragma unroll
        for (int r = 0; r < 4; ++r)
            if (r == dsp) { sv[0] = part[r][0]; sv[1] = part[r][1]; sv[2] = part[r][2]; sv[3] = part[r][3]; }
        const int i = iq * 4 + dsp;
        const int jbase = jt * 64 + jq * 4;
        const float4 qa = *(const float4*)&qre_s[i][0];
        const float4 qb = *(const float4*)&qre_s[i][4];
        #pragma unroll
        for (int c = 0; c < 4; ++c) {
            const int j = jbase + c;
            const uint4 cv = cnt[((size_t)(b * SS + i0 + i)) * SS + j];
            float s = sv[c]
                + qa.x * (float)(cv.x & 0xffff) + qa.y * (float)(cv.x >> 16)
                + qa.z * (float)(cv.y & 0xffff) + qa.w * (float)(cv.y >> 16)
                + qb.x * (float)(cv.z & 0xffff) + qb.y * (float)(cv.z >> 16)
                + qb.z * (float)(cv.w & 0xffff) + qb.w * (float)(cv.w >> 16);
            s *= 0.125f;
            const int m = mask[((size_t)(b * SS + i0 + i)) * SS + j];
            s_t[j][i] = m ? s : -1e9f;
        }
        __syncthreads();
    }

    // ---- phase 3: softmax per row i; wave w handles rows w*4..w*4+3 ----
    {
        const int wave = t >> 6, lane = t & 63;
        #pragma unroll
        for (int rr = 0; rr < 4; ++rr) {
            const int i = wave * 4 + rr;
            float v0 = s_t[lane][i], v1 = s_t[lane + 64][i],
                  v2 = s_t[lane + 128][i], v3 = s_t[lane + 192][i];
            float mx = fmaxf(fmaxf(v0, v1), fmaxf(v2, v3));
            #pragma unroll
            for (int off = 32; off > 0; off >>= 1) mx = fmaxf(mx, __shfl_xor(mx, off));
            float e0 = __expf(v0 - mx), e1 = __expf(v1 - mx),
                  e2 = __expf(v2 - mx), e3 = __expf(v3 - mx);
            float sm = e0 + e1 + e2 + e3;
            #pragma unroll
            for (int off = 32; off > 0; off >>= 1) sm += __shfl_xor(sm, off);
            const float inv = 1.f / sm;
            s_t[lane][i] = e0 * inv;
            s_t[lane + 64][i] = e1 * inv;
            s_t[lane + 128][i] = e2 * inv;
            s_t[lane + 192][i] = e3 * inv;
        }
    }
    __syncthreads();

    // ---- phase 4: PV; thread = (iq, jsub, dq), 16-output register tile ----
    {
        const int jsub = (t >> 4) & 3, dq = t & 15;
        float o[4][4] = {};
        for (int jt = 0; jt < 4; ++jt) {
            // stage V tile natural layout kv[j'][d]
            {
                const int jr = t >> 2, seg = t & 3;
                const float* src = &V0[((size_t)(b * SS + jt * 64 + jr)) * HID + h * DD + seg * 16];
                #pragma unroll
                for (int qq = 0; qq < 4; ++qq)
                    *(float4*)&kv[jr][seg * 16 + qq * 4] = *(const float4*)&src[qq * 4];
            }
            __syncthreads();
            #pragma unroll
            for (int jj = 0; jj < 16; ++jj) {
                const int j = jsub * 16 + jj;
                const float4 p4 = *(const float4*)&s_t[jt * 64 + j][iq * 4];
                const float4 v4 = *(const float4*)&kv[j][dq * 4];
                o[0][0] += p4.x * v4.x; o[0][1] += p4.x * v4.y;
                o[0][2] += p4.x * v4.z; o[0][3] += p4.x * v4.w;
                o[1][0] += p4.y * v4.x; o[1][1] += p4.y * v4.y;
                o[1][2] += p4.y * v4.z; o[1][3] += p4.y * v4.w;
                o[2][0] += p4.z * v4.x; o[2][1] += p4.z * v4.y;
                o[2][2] += p4.z * v4.z; o[2][3] += p4.z * v4.w;
                o[3][0] += p4.w * v4.x; o[3][1] += p4.w * v4.y;
                o[3][2] += p4.w * v4.z; o[3][3] += p4.w * v4.w;
            }
            __syncthreads();
        }
        // combine over jsub (lane bits 4,5)
        #pragma unroll
        for (int r = 0; r < 4; ++r)
            #pragma unroll
            for (int c = 0; c < 4; ++c) {
                float v = o[r][c];
                v += __shfl_xor(v, 16);
                v += __shfl_xor(v, 32);
                o[r][c] = v;
            }
        // thread writes row i = iq*4 + jsub, cols dq*4..+3
        float sel0 = 0.f, sel1 = 0.f, sel2 = 0.f, sel3 = 0.f;
        #pragma unroll
        for (int r = 0; r < 4; ++r)
            if (r == jsub) { sel0 = o[r][0]; sel1 = o[r][1]; sel2 = o[r][2]; sel3 = o[r][3]; }
        const int i = iq * 4 + jsub;
        float4 ov; ov.x = sel0; ov.y = sel1; ov.z = sel2; ov.w = sel3;
        *(float4*)&out[((size_t)(b * SS + i0 + i)) * HID + h * DD + dq * 4] = ov;
    }
}

extern "C" void kernel_launch(void* const* d_in, const int* in_sizes, int n_in,
                              void* d_out, int out_size, void* d_ws, size_t ws_size,
                              hipStream_t stream) {
    const float* q_hs = (const float*)d_in[0];
    const float* k_hs = (const float*)d_in[1];
    const float* v_hs = (const float*)d_in[2];
    const float* Wq   = (const float*)d_in[3];
    const float* bq   = (const float*)d_in[4];
    const float* Wk   = (const float*)d_in[5];
    const float* bk   = (const float*)d_in[6];
    const float* Wv   = (const float*)d_in[7];
    const float* bv   = (const float*)d_in[8];
    const float* rel  = (const float*)d_in[9];
    const int* edge   = (const int*)d_in[10];
    const int* mask   = (const int*)d_in[11];
    float* out = (float*)d_out;

    char* ws = (char*)d_ws;
    float* Q   = (float*)(ws);                       // 2 MB [B,S,HID]
    float* K0  = (float*)(ws + (2u << 20));          // 2 MB
    float* V0  = (float*)(ws + (4u << 20));          // 2 MB
    uint4* cnt = (uint4*)(ws + (6u << 20));          // 4 MB [B,S,S] packed u16x8

    {
        dim3 grid(1024 / 64, HID / 64, 3);
        qkv_gemm<<<grid, 512, 0, stream>>>(q_hs, k_hs, v_hs, Wq, Wk, Wv,
                                           bq, bk, bv, Q, K0, V0);
    }
    cnt_kernel<<<dim3(BB * SS / 4), 256, 0, stream>>>(edge, cnt);
    attn_fused<<<dim3(BB * NHD * (SS / IT)), 256, 0, stream>>>(Q, K0, V0, rel, cnt, mask, out);
}

// Round 6
// 128.356 us; speedup vs baseline: 2.0186x; 1.0864x over previous
//
#include <hip/hip_runtime.h>
#include <math.h>

#define BB 4
#define SS 256
#define HID 512
#define NHD 8
#define DD 64
#define IT 16

typedef __attribute__((ext_vector_type(8))) short short8v;   // 8 bf16
typedef __attribute__((ext_vector_type(4))) float f32x4;

static __device__ __forceinline__ ushort f2bf(float x) {
    uint u = __float_as_uint(x);
    uint r = u + 0x7fffu + ((u >> 16) & 1u);   // RNE
    return (ushort)(r >> 16);
}
static __device__ __forceinline__ float bf2f(ushort h) {
    return __uint_as_float(((uint)h) << 16);
}

// ---------------- pre-pass 1: X -> bf16 hi/lo ----------------
__global__ __launch_bounds__(256) void conv_x(
    const float* __restrict__ xq, const float* __restrict__ xk, const float* __restrict__ xv,
    ushort* __restrict__ Xhi, ushort* __restrict__ Xlo)
{
    const int z = blockIdx.z;
    const float* X = (z == 0) ? xq : (z == 1) ? xk : xv;
    const size_t base = (size_t)(blockIdx.x * 256 + threadIdx.x) * 4;
    const float4 v = *(const float4*)&X[base];
    ushort4 hi, lo;
    hi.x = f2bf(v.x); lo.x = f2bf(v.x - bf2f(hi.x));
    hi.y = f2bf(v.y); lo.y = f2bf(v.y - bf2f(hi.y));
    hi.z = f2bf(v.z); lo.z = f2bf(v.z - bf2f(hi.z));
    hi.w = f2bf(v.w); lo.w = f2bf(v.w - bf2f(hi.w));
    const size_t o = (size_t)z * (1024 * 512) + base;
    *(ushort4*)&Xhi[o] = hi;
    *(ushort4*)&Xlo[o] = lo;
}

// ---------------- pre-pass 2: W -> W^T bf16 hi/lo ----------------
__global__ __launch_bounds__(256) void conv_wt(
    const float* __restrict__ wq, const float* __restrict__ wk, const float* __restrict__ wv,
    ushort* __restrict__ Whi, ushort* __restrict__ Wlo)
{
    const int z = blockIdx.z;
    const float* W = (z == 0) ? wq : (z == 1) ? wk : wv;
    __shared__ float tile[32][33];
    const int k0 = blockIdx.x * 32, n0 = blockIdx.y * 32;
    const int t = threadIdx.x;
    {
        const int r = t >> 3, c4 = (t & 7) * 4;
        *(float4*)&tile[r][c4] = *(const float4*)&W[(size_t)(k0 + r) * HID + n0 + c4];
    }
    __syncthreads();
    {
        const int n = t >> 3, kc = (t & 7) * 4;
        ushort4 hi, lo;
        float v;
        v = tile[kc + 0][n]; hi.x = f2bf(v); lo.x = f2bf(v - bf2f(hi.x));
        v = tile[kc + 1][n]; hi.y = f2bf(v); lo.y = f2bf(v - bf2f(hi.y));
        v = tile[kc + 2][n]; hi.z = f2bf(v); lo.z = f2bf(v - bf2f(hi.z));
        v = tile[kc + 3][n]; hi.w = f2bf(v); lo.w = f2bf(v - bf2f(hi.w));
        const size_t o = (size_t)z * (512 * 512) + (size_t)(n0 + n) * HID + k0 + kc;
        *(ushort4*)&Whi[o] = hi;
        *(ushort4*)&Wlo[o] = lo;
    }
}

// ---------------- QKV projection GEMM via bf16-split MFMA ----------------
// 64x64 tile, BK=32, 4 waves (each 32x32 = 2x2 frags of 16x16x32)
__global__ __launch_bounds__(256) void qkv_gemm_mfma(
    const ushort* __restrict__ Xhi, const ushort* __restrict__ Xlo,
    const ushort* __restrict__ Whi, const ushort* __restrict__ Wlo,   // transposed [n][k]
    const float* __restrict__ bq, const float* __restrict__ bk, const float* __restrict__ bv,
    float* __restrict__ oq, float* __restrict__ ok, float* __restrict__ ov)
{
    const int z = blockIdx.z;
    const float* bias = (z == 0) ? bq : (z == 1) ? bk : bv;
    float*       out  = (z == 0) ? oq : (z == 1) ? ok : ov;
    const size_t xb = (size_t)z * (1024 * 512);
    const size_t wb = (size_t)z * (512 * 512);

    __shared__ ushort As_hi[64][40];
    __shared__ ushort As_lo[64][40];
    __shared__ ushort Bs_hi[64][40];
    __shared__ ushort Bs_lo[64][40];

    const int t = threadIdx.x;
    const int wave = t >> 6, lane = t & 63;
    const int wr = wave >> 1, wc = wave & 1;
    const int bm = blockIdx.x * 64, bn = blockIdx.y * 64;

    const int sm = t >> 2, sk = (t & 3) * 8;     // staging: row, k-chunk
    const int fr = lane & 15, kb = (lane >> 4) * 8;

    f32x4 acc[2][2] = {};

    for (int k0 = 0; k0 < HID; k0 += 32) {
        *(uint4*)&As_hi[sm][sk] = *(const uint4*)&Xhi[xb + (size_t)(bm + sm) * HID + k0 + sk];
        *(uint4*)&As_lo[sm][sk] = *(const uint4*)&Xlo[xb + (size_t)(bm + sm) * HID + k0 + sk];
        *(uint4*)&Bs_hi[sm][sk] = *(const uint4*)&Whi[wb + (size_t)(bn + sm) * HID + k0 + sk];
        *(uint4*)&Bs_lo[sm][sk] = *(const uint4*)&Wlo[wb + (size_t)(bn + sm) * HID + k0 + sk];
        __syncthreads();

        short8v ah[2], al[2], bh[2], bl[2];
        #pragma unroll
        for (int mi = 0; mi < 2; ++mi) {
            ah[mi] = *(const short8v*)&As_hi[wr * 32 + mi * 16 + fr][kb];
            al[mi] = *(const short8v*)&As_lo[wr * 32 + mi * 16 + fr][kb];
        }
        #pragma unroll
        for (int ni = 0; ni < 2; ++ni) {
            bh[ni] = *(const short8v*)&Bs_hi[wc * 32 + ni * 16 + fr][kb];
            bl[ni] = *(const short8v*)&Bs_lo[wc * 32 + ni * 16 + fr][kb];
        }
        #pragma unroll
        for (int mi = 0; mi < 2; ++mi)
            #pragma unroll
            for (int ni = 0; ni < 2; ++ni) {
                acc[mi][ni] = __builtin_amdgcn_mfma_f32_16x16x32_bf16(ah[mi], bh[ni], acc[mi][ni], 0, 0, 0);
                acc[mi][ni] = __builtin_amdgcn_mfma_f32_16x16x32_bf16(ah[mi], bl[ni], acc[mi][ni], 0, 0, 0);
                acc[mi][ni] = __builtin_amdgcn_mfma_f32_16x16x32_bf16(al[mi], bh[ni], acc[mi][ni], 0, 0, 0);
            }
        __syncthreads();
    }

    // epilogue: D row = (lane>>4)*4 + q, col = lane&15  [m89-verified layout]
    const int r0 = bm + wr * 32 + (lane >> 4) * 4;
    const int c0 = bn + wc * 32 + (lane & 15);
    #pragma unroll
    for (int ni = 0; ni < 2; ++ni) {
        const float bia = bias[c0 + ni * 16];
        #pragma unroll
        for (int mi = 0; mi < 2; ++mi)
            #pragma unroll
            for (int q = 0; q < 4; ++q)
                out[(size_t)(r0 + mi * 16 + q) * HID + c0 + ni * 16] = acc[mi][ni][q] + bia;
    }
}

// ---------------- parallel cumulative histogram (wave scan) ----------------
__global__ __launch_bounds__(256) void cnt_kernel(
    const int* __restrict__ edge, uint4* __restrict__ cnt)
{
    const int wave = threadIdx.x >> 6, lane = threadIdx.x & 63;
    const int col = blockIdx.x * 4 + wave;
    const int b = col / SS, j = col % SS;

    uint4 run = make_uint4(0, 0, 0, 0);
    uint4 c[4];
    #pragma unroll
    for (int r = 0; r < 4; ++r) {
        const int e = edge[((size_t)(b * SS + lane * 4 + r)) * SS + j];
        const unsigned inc = 1u << ((e & 1) * 16);
        const int comp = e >> 1;
        run.x += (comp == 0) ? inc : 0u;
        run.y += (comp == 1) ? inc : 0u;
        run.z += (comp == 2) ? inc : 0u;
        run.w += (comp == 3) ? inc : 0u;
        c[r] = run;
    }
    uint4 tot = run;
    #pragma unroll
    for (int off = 1; off < 64; off <<= 1) {
        uint4 t;
        t.x = __shfl_up((int)tot.x, off);
        t.y = __shfl_up((int)tot.y, off);
        t.z = __shfl_up((int)tot.z, off);
        t.w = __shfl_up((int)tot.w, off);
        if (lane >= off) { tot.x += t.x; tot.y += t.y; tot.z += t.z; tot.w += t.w; }
    }
    const uint4 excl = make_uint4(tot.x - run.x, tot.y - run.y, tot.z - run.z, tot.w - run.w);
    #pragma unroll
    for (int r = 0; r < 4; ++r) {
        uint4 o = make_uint4(excl.x + c[r].x, excl.y + c[r].y, excl.z + c[r].z, excl.w + c[r].w);
        cnt[((size_t)(b * SS + lane * 4 + r)) * SS + j] = o;
    }
}

// ---------------- fused attention (qrow+qre computed in-block) ----------------
__global__ __launch_bounds__(256) void attn_fused(
    const float* __restrict__ Q0,
    const float* __restrict__ K0,
    const float* __restrict__ V0,
    const float* __restrict__ rel,
    const uint4* __restrict__ cnt,
    const int* __restrict__ mask,
    float* __restrict__ out)
{
    const int x = blockIdx.x;
    const int it = x & 15;
    const int h  = (x >> 4) & 7;
    const int b  = x >> 7;
    const int i0 = it * IT;
    const int t = threadIdx.x;

    __shared__ float qst[DD][20];
    __shared__ float qre_s[IT][8];
    __shared__ float s_t[SS][20];
    __shared__ float kv[DD][68];

    {
        const int d4 = t >> 4, i = t & 15;
        const float4 q4 = *(const float4*)&Q0[((size_t)(b * SS + i0 + i)) * HID + h * DD + d4 * 4];
        const uint4 cv = cnt[((size_t)(b * SS + i0 + i)) * SS + (i0 + i)];
        float c[8];
        c[0] = (float)(cv.x & 0xffff); c[1] = (float)(cv.x >> 16);
        c[2] = (float)(cv.y & 0xffff); c[3] = (float)(cv.y >> 16);
        c[4] = (float)(cv.z & 0xffff); c[5] = (float)(cv.z >> 16);
        c[6] = (float)(cv.w & 0xffff); c[7] = (float)(cv.w >> 16);
        float o0 = q4.x, o1 = q4.y, o2 = q4.z, o3 = q4.w;
        #pragma unroll
        for (int e = 0; e < 8; ++e) {
            const float4 r4 = *(const float4*)&rel[e * HID + h * DD + d4 * 4];
            o0 += c[e] * r4.x; o1 += c[e] * r4.y; o2 += c[e] * r4.z; o3 += c[e] * r4.w;
        }
        qst[d4 * 4 + 0][i] = o0;
        qst[d4 * 4 + 1][i] = o1;
        qst[d4 * 4 + 2][i] = o2;
        qst[d4 * 4 + 3][i] = o3;
    }
    __syncthreads();

    if (t < 128) {
        const int i = t >> 3, e = t & 7;
        const float* rp = &rel[e * HID + h * DD];
        float s = 0.f;
        #pragma unroll 8
        for (int d = 0; d < DD; ++d) s += qst[d][i] * rp[d];
        qre_s[i][e] = s;
    }
    __syncthreads();

    const int iq = t >> 6;
    const int dsp = (t >> 4) & 3;
    const int jq = t & 15;
    for (int jt = 0; jt < 4; ++jt) {
        {
            const int jr = t >> 2, seg = t & 3;
            const float* src = &K0[((size_t)(b * SS + jt * 64 + jr)) * HID + h * DD + seg * 16];
            const float4 a0 = *(const float4*)&src[0];
            const float4 a1 = *(const float4*)&src[4];
            const float4 a2 = *(const float4*)&src[8];
            const float4 a3 = *(const float4*)&src[12];
            kv[seg * 16 +  0][jr] = a0.x; kv[seg * 16 +  1][jr] = a0.y;
            kv[seg * 16 +  2][jr] = a0.z; kv[seg * 16 +  3][jr] = a0.w;
            kv[seg * 16 +  4][jr] = a1.x; kv[seg * 16 +  5][jr] = a1.y;
            kv[seg * 16 +  6][jr] = a1.z; kv[seg * 16 +  7][jr] = a1.w;
            kv[seg * 16 +  8][jr] = a2.x; kv[seg * 16 +  9][jr] = a2.y;
            kv[seg * 16 + 10][jr] = a2.z; kv[seg * 16 + 11][jr] = a2.w;
            kv[seg * 16 + 12][jr] = a3.x; kv[seg * 16 + 13][jr] = a3.y;
            kv[seg * 16 + 14][jr] = a3.z; kv[seg * 16 + 15][jr] = a3.w;
        }
        __syncthreads();

        float part[4][4] = {};
        #pragma unroll
        for (int dd = 0; dd < 16; ++dd) {
            const int d = dsp * 16 + dd;
            const float4 q4 = *(const float4*)&qst[d][iq * 4];
            const float4 k4 = *(const float4*)&kv[d][jq * 4];
            part[0][0] += q4.x * k4.x; part[0][1] += q4.x * k4.y;
            part[0][2] += q4.x * k4.z; part[0][3] += q4.x * k4.w;
            part[1][0] += q4.y * k4.x; part[1][1] += q4.y * k4.y;
            part[1][2] += q4.y * k4.z; part[1][3] += q4.y * k4.w;
            part[2][0] += q4.z * k4.x; part[2][1] += q4.z * k4.y;
            part[2][2] += q4.z * k4.z; part[2][3] += q4.z * k4.w;
            part[3][0] += q4.w * k4.x; part[3][1] += q4.w * k4.y;
            part[3][2] += q4.w * k4.z; part[3][3] += q4.w * k4.w;
        }
        #pragma unroll
        for (int r = 0; r < 4; ++r)
            #pragma unroll
            for (int c = 0; c < 4; ++c) {
                float v = part[r][c];
                v += __shfl_xor(v, 16);
                v += __shfl_xor(v, 32);
                part[r][c] = v;
            }
        float sv[4];
        #pragma unroll
        for (int r = 0; r < 4; ++r)
            if (r == dsp) { sv[0] = part[r][0]; sv[1] = part[r][1]; sv[2] = part[r][2]; sv[3] = part[r][3]; }
        const int i = iq * 4 + dsp;
        const int jbase = jt * 64 + jq * 4;
        const float4 qa = *(const float4*)&qre_s[i][0];
        const float4 qb = *(const float4*)&qre_s[i][4];
        #pragma unroll
        for (int c = 0; c < 4; ++c) {
            const int j = jbase + c;
            const uint4 cv = cnt[((size_t)(b * SS + i0 + i)) * SS + j];
            float s = sv[c]
                + qa.x * (float)(cv.x & 0xffff) + qa.y * (float)(cv.x >> 16)
                + qa.z * (float)(cv.y & 0xffff) + qa.w * (float)(cv.y >> 16)
                + qb.x * (float)(cv.z & 0xffff) + qb.y * (float)(cv.z >> 16)
                + qb.z * (float)(cv.w & 0xffff) + qb.w * (float)(cv.w >> 16);
            s *= 0.125f;
            const int m = mask[((size_t)(b * SS + i0 + i)) * SS + j];
            s_t[j][i] = m ? s : -1e9f;
        }
        __syncthreads();
    }

    {
        const int wave = t >> 6, lane = t & 63;
        #pragma unroll
        for (int rr = 0; rr < 4; ++rr) {
            const int i = wave * 4 + rr;
            float v0 = s_t[lane][i], v1 = s_t[lane + 64][i],
                  v2 = s_t[lane + 128][i], v3 = s_t[lane + 192][i];
            float mx = fmaxf(fmaxf(v0, v1), fmaxf(v2, v3));
            #pragma unroll
            for (int off = 32; off > 0; off >>= 1) mx = fmaxf(mx, __shfl_xor(mx, off));
            float e0 = __expf(v0 - mx), e1 = __expf(v1 - mx),
                  e2 = __expf(v2 - mx), e3 = __expf(v3 - mx);
            float sm = e0 + e1 + e2 + e3;
            #pragma unroll
            for (int off = 32; off > 0; off >>= 1) sm += __shfl_xor(sm, off);
            const float inv = 1.f / sm;
            s_t[lane][i] = e0 * inv;
            s_t[lane + 64][i] = e1 * inv;
            s_t[lane + 128][i] = e2 * inv;
            s_t[lane + 192][i] = e3 * inv;
        }
    }
    __syncthreads();

    {
        const int jsub = (t >> 4) & 3, dq = t & 15;
        float o[4][4] = {};
        for (int jt = 0; jt < 4; ++jt) {
            {
                const int jr = t >> 2, seg = t & 3;
                const float* src = &V0[((size_t)(b * SS + jt * 64 + jr)) * HID + h * DD + seg * 16];
                #pragma unroll
                for (int qq = 0; qq < 4; ++qq)
                    *(float4*)&kv[jr][seg * 16 + qq * 4] = *(const float4*)&src[qq * 4];
            }
            __syncthreads();
            #pragma unroll
            for (int jj = 0; jj < 16; ++jj) {
                const int j = jsub * 16 + jj;
                const float4 p4 = *(const float4*)&s_t[jt * 64 + j][iq * 4];
                const float4 v4 = *(const float4*)&kv[j][dq * 4];
                o[0][0] += p4.x * v4.x; o[0][1] += p4.x * v4.y;
                o[0][2] += p4.x * v4.z; o[0][3] += p4.x * v4.w;
                o[1][0] += p4.y * v4.x; o[1][1] += p4.y * v4.y;
                o[1][2] += p4.y * v4.z; o[1][3] += p4.y * v4.w;
                o[2][0] += p4.z * v4.x; o[2][1] += p4.z * v4.y;
                o[2][2] += p4.z * v4.z; o[2][3] += p4.z * v4.w;
                o[3][0] += p4.w * v4.x; o[3][1] += p4.w * v4.y;
                o[3][2] += p4.w * v4.z; o[3][3] += p4.w * v4.w;
            }
            __syncthreads();
        }
        #pragma unroll
        for (int r = 0; r < 4; ++r)
            #pragma unroll
            for (int c = 0; c < 4; ++c) {
                float v = o[r][c];
                v += __shfl_xor(v, 16);
                v += __shfl_xor(v, 32);
                o[r][c] = v;
            }
        float sel0 = 0.f, sel1 = 0.f, sel2 = 0.f, sel3 = 0.f;
        #pragma unroll
        for (int r = 0; r < 4; ++r)
            if (r == jsub) { sel0 = o[r][0]; sel1 = o[r][1]; sel2 = o[r][2]; sel3 = o[r][3]; }
        const int i = iq * 4 + jsub;
        float4 ov; ov.x = sel0; ov.y = sel1; ov.z = sel2; ov.w = sel3;
        *(float4*)&out[((size_t)(b * SS + i0 + i)) * HID + h * DD + dq * 4] = ov;
    }
}

extern "C" void kernel_launch(void* const* d_in, const int* in_sizes, int n_in,
                              void* d_out, int out_size, void* d_ws, size_t ws_size,
                              hipStream_t stream) {
    const float* q_hs = (const float*)d_in[0];
    const float* k_hs = (const float*)d_in[1];
    const float* v_hs = (const float*)d_in[2];
    const float* Wq   = (const float*)d_in[3];
    const float* bq   = (const float*)d_in[4];
    const float* Wk   = (const float*)d_in[5];
    const float* bk   = (const float*)d_in[6];
    const float* Wv   = (const float*)d_in[7];
    const float* bv   = (const float*)d_in[8];
    const float* rel  = (const float*)d_in[9];
    const int* edge   = (const int*)d_in[10];
    const int* mask   = (const int*)d_in[11];
    float* out = (float*)d_out;

    char* ws = (char*)d_ws;
    float*  Q    = (float*)(ws);                         // 2 MB [B,S,HID]
    float*  K0   = (float*)(ws + (2u  << 20));           // 2 MB
    float*  V0   = (float*)(ws + (4u  << 20));           // 2 MB
    uint4*  cnt  = (uint4*)(ws + (6u  << 20));           // 4 MB
    ushort* Xhi  = (ushort*)(ws + (10u << 20));          // 3 MB
    ushort* Xlo  = (ushort*)(ws + (13u << 20));          // 3 MB
    ushort* Wthi = (ushort*)(ws + (16u << 20));          // 1.5 MB
    ushort* Wtlo = (ushort*)(ws + (18u << 20));          // 1.5 MB

    conv_x<<<dim3(512, 1, 3), 256, 0, stream>>>(q_hs, k_hs, v_hs, Xhi, Xlo);
    conv_wt<<<dim3(16, 16, 3), 256, 0, stream>>>(Wq, Wk, Wv, Wthi, Wtlo);
    {
        dim3 grid(1024 / 64, HID / 64, 3);
        qkv_gemm_mfma<<<grid, 256, 0, stream>>>(Xhi, Xlo, Wthi, Wtlo,
                                                bq, bk, bv, Q, K0, V0);
    }
    cnt_kernel<<<dim3(BB * SS / 4), 256, 0, stream>>>(edge, cnt);
    attn_fused<<<dim3(BB * NHD * (SS / IT)), 256, 0, stream>>>(Q, K0, V0, rel, cnt, mask, out);
}

// Round 8
// 117.686 us; speedup vs baseline: 2.2016x; 1.0907x over previous
//
#include <hip/hip_runtime.h>
#include <math.h>

#define BB 4
#define SS 256
#define HID 512
#define NHD 8
#define DD 64
#define IT 16

typedef __attribute__((ext_vector_type(8))) short short8v;   // 8 bf16
typedef __attribute__((ext_vector_type(4))) float f32x4;

static __device__ __forceinline__ ushort f2bf(float x) {
    uint u = __float_as_uint(x);
    uint r = u + 0x7fffu + ((u >> 16) & 1u);   // RNE
    return (ushort)(r >> 16);
}
static __device__ __forceinline__ float bf2f(ushort h) {
    return __uint_as_float(((uint)h) << 16);
}
static __device__ __forceinline__ void cvt8(const float4& a, const float4& b,
                                            short8v& hi, short8v& lo) {
    ushort h;
    h = f2bf(a.x); hi[0] = (short)h; lo[0] = (short)f2bf(a.x - bf2f(h));
    h = f2bf(a.y); hi[1] = (short)h; lo[1] = (short)f2bf(a.y - bf2f(h));
    h = f2bf(a.z); hi[2] = (short)h; lo[2] = (short)f2bf(a.z - bf2f(h));
    h = f2bf(a.w); hi[3] = (short)h; lo[3] = (short)f2bf(a.w - bf2f(h));
    h = f2bf(b.x); hi[4] = (short)h; lo[4] = (short)f2bf(b.x - bf2f(h));
    h = f2bf(b.y); hi[5] = (short)h; lo[5] = (short)f2bf(b.y - bf2f(h));
    h = f2bf(b.z); hi[6] = (short)h; lo[6] = (short)f2bf(b.z - bf2f(h));
    h = f2bf(b.w); hi[7] = (short)h; lo[7] = (short)f2bf(b.w - bf2f(h));
}

// ---------------- prep: cnt scan (blocks 0..255) + W^T bf16 conv (blocks 256..1023) ----------------
__global__ __launch_bounds__(256) void prep_kernel(
    const int* __restrict__ edge, uint4* __restrict__ cnt,
    const float* __restrict__ wq, const float* __restrict__ wk, const float* __restrict__ wv,
    ushort* __restrict__ Whi, ushort* __restrict__ Wlo)
{
    __shared__ float tile[32][33];
    const int bid = blockIdx.x;
    const int t = threadIdx.x;

    if (bid < 256) {
        // cumulative histogram: one wave per column (b,j), packed 8 x u16
        const int wave = t >> 6, lane = t & 63;
        const int col = bid * 4 + wave;
        const int b = col / SS, j = col % SS;

        uint4 run = make_uint4(0, 0, 0, 0);
        uint4 c[4];
        #pragma unroll
        for (int r = 0; r < 4; ++r) {
            const int e = edge[((size_t)(b * SS + lane * 4 + r)) * SS + j];
            const unsigned inc = 1u << ((e & 1) * 16);
            const int comp = e >> 1;
            run.x += (comp == 0) ? inc : 0u;
            run.y += (comp == 1) ? inc : 0u;
            run.z += (comp == 2) ? inc : 0u;
            run.w += (comp == 3) ? inc : 0u;
            c[r] = run;
        }
        uint4 tot = run;
        #pragma unroll
        for (int off = 1; off < 64; off <<= 1) {
            uint4 s;
            s.x = __shfl_up((int)tot.x, off);
            s.y = __shfl_up((int)tot.y, off);
            s.z = __shfl_up((int)tot.z, off);
            s.w = __shfl_up((int)tot.w, off);
            if (lane >= off) { tot.x += s.x; tot.y += s.y; tot.z += s.z; tot.w += s.w; }
        }
        const uint4 excl = make_uint4(tot.x - run.x, tot.y - run.y, tot.z - run.z, tot.w - run.w);
        #pragma unroll
        for (int r = 0; r < 4; ++r) {
            uint4 o = make_uint4(excl.x + c[r].x, excl.y + c[r].y, excl.z + c[r].z, excl.w + c[r].w);
            cnt[((size_t)(b * SS + lane * 4 + r)) * SS + j] = o;
        }
    } else {
        const int v = bid - 256;
        const int bx = v & 15, by = (v >> 4) & 15, z = v >> 8;
        const float* W = (z == 0) ? wq : (z == 1) ? wk : wv;
        const int k0 = bx * 32, n0 = by * 32;
        {
            const int r = t >> 3, c4 = (t & 7) * 4;
            *(float4*)&tile[r][c4] = *(const float4*)&W[(size_t)(k0 + r) * HID + n0 + c4];
        }
        __syncthreads();
        {
            const int n = t >> 3, kc = (t & 7) * 4;
            ushort4 hi, lo;
            float x;
            x = tile[kc + 0][n]; hi.x = f2bf(x); lo.x = f2bf(x - bf2f(hi.x));
            x = tile[kc + 1][n]; hi.y = f2bf(x); lo.y = f2bf(x - bf2f(hi.y));
            x = tile[kc + 2][n]; hi.z = f2bf(x); lo.z = f2bf(x - bf2f(hi.z));
            x = tile[kc + 3][n]; hi.w = f2bf(x); lo.w = f2bf(x - bf2f(hi.w));
            const size_t o = (size_t)z * (512 * 512) + (size_t)(n0 + n) * HID + k0 + kc;
            *(ushort4*)&Whi[o] = hi;
            *(ushort4*)&Wlo[o] = lo;
        }
    }
}

// ---------------- QKV GEMM: fp32 X converted in-staging, bf16-split MFMA ----------------
__global__ __launch_bounds__(256) void qkv_gemm_mfma(
    const float* __restrict__ xq, const float* __restrict__ xk, const float* __restrict__ xv,
    const ushort* __restrict__ Whi, const ushort* __restrict__ Wlo,   // [z][n][k] bf16
    const float* __restrict__ bq, const float* __restrict__ bk, const float* __restrict__ bv,
    float* __restrict__ oq, float* __restrict__ ok, float* __restrict__ ov)
{
    const int z = blockIdx.z;
    const float* X    = (z == 0) ? xq : (z == 1) ? xk : xv;
    const float* bias = (z == 0) ? bq : (z == 1) ? bk : bv;
    float*       out  = (z == 0) ? oq : (z == 1) ? ok : ov;
    const size_t wb = (size_t)z * (512 * 512);

    __shared__ ushort As_hi[64][40];
    __shared__ ushort As_lo[64][40];
    __shared__ ushort Bs_hi[64][40];
    __shared__ ushort Bs_lo[64][40];

    const int t = threadIdx.x;
    const int wave = t >> 6, lane = t & 63;
    const int wr = wave >> 1, wc = wave & 1;
    const int bm = blockIdx.x * 64, bn = blockIdx.y * 64;

    const int sm = t >> 2, sk = (t & 3) * 8;
    const int fr = lane & 15, kb = (lane >> 4) * 8;

    f32x4 acc[2][2] = {};

    for (int k0 = 0; k0 < HID; k0 += 32) {
        {
            const float* xp = &X[(size_t)(bm + sm) * HID + k0 + sk];
            const float4 a0 = *(const float4*)&xp[0];
            const float4 a1 = *(const float4*)&xp[4];
            short8v h8, l8;
            cvt8(a0, a1, h8, l8);
            *(short8v*)&As_hi[sm][sk] = h8;
            *(short8v*)&As_lo[sm][sk] = l8;
        }
        *(uint4*)&Bs_hi[sm][sk] = *(const uint4*)&Whi[wb + (size_t)(bn + sm) * HID + k0 + sk];
        *(uint4*)&Bs_lo[sm][sk] = *(const uint4*)&Wlo[wb + (size_t)(bn + sm) * HID + k0 + sk];
        __syncthreads();

        short8v ah[2], al[2], bh[2], bl[2];
        #pragma unroll
        for (int mi = 0; mi < 2; ++mi) {
            ah[mi] = *(const short8v*)&As_hi[wr * 32 + mi * 16 + fr][kb];
            al[mi] = *(const short8v*)&As_lo[wr * 32 + mi * 16 + fr][kb];
        }
        #pragma unroll
        for (int ni = 0; ni < 2; ++ni) {
            bh[ni] = *(const short8v*)&Bs_hi[wc * 32 + ni * 16 + fr][kb];
            bl[ni] = *(const short8v*)&Bs_lo[wc * 32 + ni * 16 + fr][kb];
        }
        #pragma unroll
        for (int mi = 0; mi < 2; ++mi)
            #pragma unroll
            for (int ni = 0; ni < 2; ++ni) {
                acc[mi][ni] = __builtin_amdgcn_mfma_f32_16x16x32_bf16(ah[mi], bh[ni], acc[mi][ni], 0, 0, 0);
                acc[mi][ni] = __builtin_amdgcn_mfma_f32_16x16x32_bf16(ah[mi], bl[ni], acc[mi][ni], 0, 0, 0);
                acc[mi][ni] = __builtin_amdgcn_mfma_f32_16x16x32_bf16(al[mi], bh[ni], acc[mi][ni], 0, 0, 0);
            }
        __syncthreads();
    }

    const int r0 = bm + wr * 32 + (lane >> 4) * 4;
    const int c0 = bn + wc * 32 + (lane & 15);
    #pragma unroll
    for (int ni = 0; ni < 2; ++ni) {
        const float bia = bias[c0 + ni * 16];
        #pragma unroll
        for (int mi = 0; mi < 2; ++mi)
            #pragma unroll
            for (int q = 0; q < 4; ++q)
                out[(size_t)(r0 + mi * 16 + q) * HID + c0 + ni * 16] = acc[mi][ni][q] + bia;
    }
}

// ---------------- fused attention: MFMA QK^T, VALU PV ----------------
__global__ __launch_bounds__(256) void attn_fused(
    const float* __restrict__ Q0,
    const float* __restrict__ K0,
    const float* __restrict__ V0,
    const float* __restrict__ rel,
    const uint4* __restrict__ cnt,
    const int* __restrict__ mask,
    float* __restrict__ out)
{
    const int x = blockIdx.x;
    const int it = x & 15;
    const int h  = (x >> 4) & 7;
    const int b  = x >> 7;
    const int i0 = it * IT;
    const int t = threadIdx.x, wave = t >> 6, lane = t & 63;

    __shared__ ushort qhi[16][72];     // qrow bf16 hi, row stride 144B (16B-aligned)
    __shared__ ushort qlo[16][72];
    __shared__ float qre_s[IT][8];
    __shared__ float s_t[SS][20];      // scores/probs [j][i]
    __shared__ float vtile[64][68];    // V tile [j'][d]

    // ---- phase 0a: qrow = Q0 + sum_e cntdiag[e]*rel[e]; cvt to bf16 hi/lo ----
    const int pi = t >> 4, pd = t & 15;
    float4 qr4;
    {
        const float4 q4 = *(const float4*)&Q0[((size_t)(b * SS + i0 + pi)) * HID + h * DD + pd * 4];
        const uint4 cv = cnt[((size_t)(b * SS + i0 + pi)) * SS + (i0 + pi)];
        float c[8];
        c[0] = (float)(cv.x & 0xffff); c[1] = (float)(cv.x >> 16);
        c[2] = (float)(cv.y & 0xffff); c[3] = (float)(cv.y >> 16);
        c[4] = (float)(cv.z & 0xffff); c[5] = (float)(cv.z >> 16);
        c[6] = (float)(cv.w & 0xffff); c[7] = (float)(cv.w >> 16);
        float o0 = q4.x, o1 = q4.y, o2 = q4.z, o3 = q4.w;
        #pragma unroll
        for (int e = 0; e < 8; ++e) {
            const float4 r4 = *(const float4*)&rel[e * HID + h * DD + pd * 4];
            o0 += c[e] * r4.x; o1 += c[e] * r4.y; o2 += c[e] * r4.z; o3 += c[e] * r4.w;
        }
        qr4.x = o0; qr4.y = o1; qr4.z = o2; qr4.w = o3;
        ushort4 h4, l4;
        h4.x = f2bf(o0); l4.x = f2bf(o0 - bf2f(h4.x));
        h4.y = f2bf(o1); l4.y = f2bf(o1 - bf2f(h4.y));
        h4.z = f2bf(o2); l4.z = f2bf(o2 - bf2f(h4.z));
        h4.w = f2bf(o3); l4.w = f2bf(o3 - bf2f(h4.w));
        *(ushort4*)&qhi[pi][pd * 4] = h4;
        *(ushort4*)&qlo[pi][pd * 4] = l4;
    }
    // ---- phase 0b: qre[i][e] via shfl-reduce over pd (lane bits 0..3) ----
    {
        float r[8];
        #pragma unroll
        for (int e = 0; e < 8; ++e) {
            const float4 rr = *(const float4*)&rel[e * HID + h * DD + pd * 4];
            r[e] = qr4.x * rr.x + qr4.y * rr.y + qr4.z * rr.z + qr4.w * rr.w;
        }
        #pragma unroll
        for (int e = 0; e < 8; ++e) {
            float v = r[e];
            v += __shfl_xor(v, 1);
            v += __shfl_xor(v, 2);
            v += __shfl_xor(v, 4);
            v += __shfl_xor(v, 8);
            r[e] = v;
        }
        float sel = 0.f;
        #pragma unroll
        for (int e = 0; e < 8; ++e) if (pd == e) sel = r[e];
        if (pd < 8) qre_s[pi][pd] = sel;
    }
    __syncthreads();

    // ---- phase 2: scores via MFMA (3-term bf16 split); wave = jt, K from global ----
    {
        const int fr = lane & 15, kb8 = (lane >> 4) * 8;
        const int jt = wave;
        const int ib = (lane >> 4) * 4;

        short8v qh[2], ql[2];
        #pragma unroll
        for (int ks = 0; ks < 2; ++ks) {
            qh[ks] = *(const short8v*)&qhi[fr][ks * 32 + kb8];
            ql[ks] = *(const short8v*)&qlo[fr][ks * 32 + kb8];
        }
        float4 qa[4], qb[4];
        #pragma unroll
        for (int q = 0; q < 4; ++q) {
            qa[q] = *(const float4*)&qre_s[ib + q][0];
            qb[q] = *(const float4*)&qre_s[ib + q][4];
        }

        #pragma unroll
        for (int jf = 0; jf < 4; ++jf) {
            const int j = jt * 64 + jf * 16 + fr;
            const float* Kr = &K0[((size_t)(b * SS + j)) * HID + h * DD];
            f32x4 acc = {};
            #pragma unroll
            for (int ks = 0; ks < 2; ++ks) {
                const float4 k0v = *(const float4*)&Kr[ks * 32 + kb8];
                const float4 k1v = *(const float4*)&Kr[ks * 32 + kb8 + 4];
                short8v kh, kl;
                cvt8(k0v, k1v, kh, kl);
                acc = __builtin_amdgcn_mfma_f32_16x16x32_bf16(qh[ks], kh, acc, 0, 0, 0);
                acc = __builtin_amdgcn_mfma_f32_16x16x32_bf16(qh[ks], kl, acc, 0, 0, 0);
                acc = __builtin_amdgcn_mfma_f32_16x16x32_bf16(ql[ks], kh, acc, 0, 0, 0);
            }
            float sv[4];
            #pragma unroll
            for (int q = 0; q < 4; ++q) {
                const int i = ib + q;
                const uint4 cv = cnt[((size_t)(b * SS + i0 + i)) * SS + j];
                float s = acc[q]
                    + qa[q].x * (float)(cv.x & 0xffff) + qa[q].y * (float)(cv.x >> 16)
                    + qa[q].z * (float)(cv.y & 0xffff) + qa[q].w * (float)(cv.y >> 16)
                    + qb[q].x * (float)(cv.z & 0xffff) + qb[q].y * (float)(cv.z >> 16)
                    + qb[q].z * (float)(cv.w & 0xffff) + qb[q].w * (float)(cv.w >> 16);
                s *= 0.125f;
                const int m = mask[((size_t)(b * SS + i0 + i)) * SS + j];
                sv[q] = m ? s : -1e9f;
            }
            float4 w4; w4.x = sv[0]; w4.y = sv[1]; w4.z = sv[2]; w4.w = sv[3];
            *(float4*)&s_t[j][ib] = w4;
        }
    }
    __syncthreads();

    // ---- phase 3: softmax per row; wave w handles rows w*4..w*4+3 ----
    {
        #pragma unroll
        for (int rr = 0; rr < 4; ++rr) {
            const int i = wave * 4 + rr;
            float v0 = s_t[lane][i], v1 = s_t[lane + 64][i],
                  v2 = s_t[lane + 128][i], v3 = s_t[lane + 192][i];
            float mx = fmaxf(fmaxf(v0, v1), fmaxf(v2, v3));
            #pragma unroll
            for (int off = 32; off > 0; off >>= 1) mx = fmaxf(mx, __shfl_xor(mx, off));
            float e0 = __expf(v0 - mx), e1 = __expf(v1 - mx),
                  e2 = __expf(v2 - mx), e3 = __expf(v3 - mx);
            float sm = e0 + e1 + e2 + e3;
            #pragma unroll
            for (int off = 32; off > 0; off >>= 1) sm += __shfl_xor(sm, off);
            const float inv = 1.f / sm;
            s_t[lane][i] = e0 * inv;
            s_t[lane + 64][i] = e1 * inv;
            s_t[lane + 128][i] = e2 * inv;
            s_t[lane + 192][i] = e3 * inv;
        }
    }
    __syncthreads();

    // ---- phase 4: PV outer-product; thread = (iq=wave, jsub, dq) ----
    {
        const int iq = wave;
        const int jsub = (t >> 4) & 3, dq = t & 15;
        float o[4][4] = {};
        for (int jt = 0; jt < 4; ++jt) {
            {
                const int jr = t >> 2, seg = t & 3;
                const float* src = &V0[((size_t)(b * SS + jt * 64 + jr)) * HID + h * DD + seg * 16];
                #pragma unroll
                for (int qq = 0; qq < 4; ++qq)
                    *(float4*)&vtile[jr][seg * 16 + qq * 4] = *(const float4*)&src[qq * 4];
            }
            __syncthreads();
            #pragma unroll
            for (int jj = 0; jj < 16; ++jj) {
                const int j = jsub * 16 + jj;
                const float4 p4 = *(const float4*)&s_t[jt * 64 + j][iq * 4];
                const float4 v4 = *(const float4*)&vtile[j][dq * 4];
                o[0][0] += p4.x * v4.x; o[0][1] += p4.x * v4.y;
                o[0][2] += p4.x * v4.z; o[0][3] += p4.x * v4.w;
                o[1][0] += p4.y * v4.x; o[1][1] += p4.y * v4.y;
                o[1][2] += p4.y * v4.z; o[1][3] += p4.y * v4.w;
                o[2][0] += p4.z * v4.x; o[2][1] += p4.z * v4.y;
                o[2][2] += p4.z * v4.z; o[2][3] += p4.z * v4.w;
                o[3][0] += p4.w * v4.x; o[3][1] += p4.w * v4.y;
                o[3][2] += p4.w * v4.z; o[3][3] += p4.w * v4.w;
            }
            __syncthreads();
        }
        #pragma unroll
        for (int r = 0; r < 4; ++r)
            #pragma unroll
            for (int c = 0; c < 4; ++c) {
                float v = o[r][c];
                v += __shfl_xor(v, 16);
                v += __shfl_xor(v, 32);
                o[r][c] = v;
            }
        float sel0 = 0.f, sel1 = 0.f, sel2 = 0.f, sel3 = 0.f;
        #pragma unroll
        for (int r = 0; r < 4; ++r)
            if (r == jsub) { sel0 = o[r][0]; sel1 = o[r][1]; sel2 = o[r][2]; sel3 = o[r][3]; }
        const int i = iq * 4 + jsub;
        float4 ov; ov.x = sel0; ov.y = sel1; ov.z = sel2; ov.w = sel3;
        *(float4*)&out[((size_t)(b * SS + i0 + i)) * HID + h * DD + dq * 4] = ov;
    }
}

extern "C" void kernel_launch(void* const* d_in, const int* in_sizes, int n_in,
                              void* d_out, int out_size, void* d_ws, size_t ws_size,
                              hipStream_t stream) {
    const float* q_hs = (const float*)d_in[0];
    const float* k_hs = (const float*)d_in[1];
    const float* v_hs = (const float*)d_in[2];
    const float* Wq   = (const float*)d_in[3];
    const float* bq   = (const float*)d_in[4];
    const float* Wk   = (const float*)d_in[5];
    const float* bk   = (const float*)d_in[6];
    const float* Wv   = (const float*)d_in[7];
    const float* bv   = (const float*)d_in[8];
    const float* rel  = (const float*)d_in[9];
    const int* edge   = (const int*)d_in[10];
    const int* mask   = (const int*)d_in[11];
    float* out = (float*)d_out;

    char* ws = (char*)d_ws;
    float*  Q    = (float*)(ws);                         // 2 MB [B,S,HID]
    float*  K0   = (float*)(ws + (2u  << 20));           // 2 MB
    float*  V0   = (float*)(ws + (4u  << 20));           // 2 MB
    uint4*  cnt  = (uint4*)(ws + (6u  << 20));           // 4 MB
    ushort* Wthi = (ushort*)(ws + (10u << 20));          // 1.5 MB [z][n][k]
    ushort* Wtlo = (ushort*)(ws + (12u << 20));          // 1.5 MB

    prep_kernel<<<dim3(1024), 256, 0, stream>>>(edge, cnt, Wq, Wk, Wv, Wthi, Wtlo);
    {
        dim3 grid(1024 / 64, HID / 64, 3);
        qkv_gemm_mfma<<<grid, 256, 0, stream>>>(q_hs, k_hs, v_hs, Wthi, Wtlo,
                                                bq, bk, bv, Q, K0, V0);
    }
    attn_fused<<<dim3(BB * NHD * (SS / IT)), 256, 0, stream>>>(Q, K0, V0, rel, cnt, mask, out);
}

// Round 10
// 113.105 us; speedup vs baseline: 2.2908x; 1.0405x over previous
//
#include <hip/hip_runtime.h>
#include <math.h>

#define BB 4
#define SS 256
#define HID 512
#define NHD 8
#define DD 64
#define IT 16

typedef __attribute__((ext_vector_type(8))) short short8v;   // 8 bf16
typedef __attribute__((ext_vector_type(4))) float f32x4;

static __device__ __forceinline__ ushort f2bf(float x) {
    uint u = __float_as_uint(x);
    uint r = u + 0x7fffu + ((u >> 16) & 1u);   // RNE
    return (ushort)(r >> 16);
}
static __device__ __forceinline__ float bf2f(ushort h) {
    return __uint_as_float(((uint)h) << 16);
}
static __device__ __forceinline__ void cvt8(const float4& a, const float4& b,
                                            short8v& hi, short8v& lo) {
    ushort h;
    h = f2bf(a.x); hi[0] = (short)h; lo[0] = (short)f2bf(a.x - bf2f(h));
    h = f2bf(a.y); hi[1] = (short)h; lo[1] = (short)f2bf(a.y - bf2f(h));
    h = f2bf(a.z); hi[2] = (short)h; lo[2] = (short)f2bf(a.z - bf2f(h));
    h = f2bf(a.w); hi[3] = (short)h; lo[3] = (short)f2bf(a.w - bf2f(h));
    h = f2bf(b.x); hi[4] = (short)h; lo[4] = (short)f2bf(b.x - bf2f(h));
    h = f2bf(b.y); hi[5] = (short)h; lo[5] = (short)f2bf(b.y - bf2f(h));
    h = f2bf(b.z); hi[6] = (short)h; lo[6] = (short)f2bf(b.z - bf2f(h));
    h = f2bf(b.w); hi[7] = (short)h; lo[7] = (short)f2bf(b.w - bf2f(h));
}

// ============ K1: blocks 0-383 = QKV GEMM (inline W transpose+cvt) | 384-639 = cnt scan ============
__global__ __launch_bounds__(256) void gemm_cnt(
    const float* __restrict__ xq, const float* __restrict__ xk, const float* __restrict__ xv,
    const float* __restrict__ wq, const float* __restrict__ wk, const float* __restrict__ wv,
    const float* __restrict__ bq, const float* __restrict__ bk, const float* __restrict__ bv,
    float* __restrict__ oq, float* __restrict__ ok, float* __restrict__ ov,
    const int* __restrict__ edge, uint4* __restrict__ cnt)
{
    const int bid = blockIdx.x;
    const int t = threadIdx.x;
    const int wave = t >> 6, lane = t & 63;

    if (bid >= 384) {
        // ---- cumulative histogram: one wave per column (b,j), packed 8 x u16 ----
        const int col = (bid - 384) * 4 + wave;
        const int b = col / SS, j = col % SS;
        uint4 run = make_uint4(0, 0, 0, 0);
        uint4 c[4];
        #pragma unroll
        for (int r = 0; r < 4; ++r) {
            const int e = edge[((size_t)(b * SS + lane * 4 + r)) * SS + j];
            const unsigned inc = 1u << ((e & 1) * 16);
            const int comp = e >> 1;
            run.x += (comp == 0) ? inc : 0u;
            run.y += (comp == 1) ? inc : 0u;
            run.z += (comp == 2) ? inc : 0u;
            run.w += (comp == 3) ? inc : 0u;
            c[r] = run;
        }
        uint4 tot = run;
        #pragma unroll
        for (int off = 1; off < 64; off <<= 1) {
            uint4 s;
            s.x = __shfl_up((int)tot.x, off);
            s.y = __shfl_up((int)tot.y, off);
            s.z = __shfl_up((int)tot.z, off);
            s.w = __shfl_up((int)tot.w, off);
            if (lane >= off) { tot.x += s.x; tot.y += s.y; tot.z += s.z; tot.w += s.w; }
        }
        const uint4 excl = make_uint4(tot.x - run.x, tot.y - run.y, tot.z - run.z, tot.w - run.w);
        #pragma unroll
        for (int r = 0; r < 4; ++r) {
            uint4 o = make_uint4(excl.x + c[r].x, excl.y + c[r].y, excl.z + c[r].z, excl.w + c[r].w);
            cnt[((size_t)(b * SS + lane * 4 + r)) * SS + j] = o;
        }
        return;
    }

    // ---- GEMM: 64x64 tile, BK=32, bf16-split MFMA; X and W converted in staging ----
    __shared__ ushort As_hi[64][40];
    __shared__ ushort As_lo[64][40];
    __shared__ ushort Bs_hi[64][40];
    __shared__ ushort Bs_lo[64][40];

    const int z = bid / 128, rr = bid % 128;
    const float* X    = (z == 0) ? xq : (z == 1) ? xk : xv;
    const float* W    = (z == 0) ? wq : (z == 1) ? wk : wv;
    const float* bias = (z == 0) ? bq : (z == 1) ? bk : bv;
    float*       out  = (z == 0) ? oq : (z == 1) ? ok : ov;
    const int bm = (rr & 15) * 64, bn = (rr >> 4) * 64;

    const int wr = wave >> 1, wc = wave & 1;
    const int sm = t >> 2, sk = (t & 3) * 8;       // X staging: row, k-chunk
    const int wn = t & 63, wks = (t >> 6) * 8;     // W staging: col n, k-chunk
    const int fr = lane & 15, kb = (lane >> 4) * 8;

    f32x4 acc[2][2] = {};

    for (int k0 = 0; k0 < HID; k0 += 32) {
        // X: row-major coalesced float4 x2, cvt to hi/lo
        {
            const float* xp = &X[(size_t)(bm + sm) * HID + k0 + sk];
            const float4 a0 = *(const float4*)&xp[0];
            const float4 a1 = *(const float4*)&xp[4];
            short8v h8, l8;
            cvt8(a0, a1, h8, l8);
            *(short8v*)&As_hi[sm][sk] = h8;
            *(short8v*)&As_lo[sm][sk] = l8;
        }
        // W: column-coalesced loads (lane=n contiguous), transpose via registers
        {
            float wv8[8];
            #pragma unroll
            for (int j = 0; j < 8; ++j)
                wv8[j] = W[(size_t)(k0 + wks + j) * HID + bn + wn];
            short8v wh, wl;
            #pragma unroll
            for (int j = 0; j < 8; ++j) {
                const ushort h = f2bf(wv8[j]);
                wh[j] = (short)h;
                wl[j] = (short)f2bf(wv8[j] - bf2f(h));
            }
            *(short8v*)&Bs_hi[wn][wks] = wh;
            *(short8v*)&Bs_lo[wn][wks] = wl;
        }
        __syncthreads();

        short8v ah[2], al[2], bh[2], bl[2];
        #pragma unroll
        for (int mi = 0; mi < 2; ++mi) {
            ah[mi] = *(const short8v*)&As_hi[wr * 32 + mi * 16 + fr][kb];
            al[mi] = *(const short8v*)&As_lo[wr * 32 + mi * 16 + fr][kb];
        }
        #pragma unroll
        for (int ni = 0; ni < 2; ++ni) {
            bh[ni] = *(const short8v*)&Bs_hi[wc * 32 + ni * 16 + fr][kb];
            bl[ni] = *(const short8v*)&Bs_lo[wc * 32 + ni * 16 + fr][kb];
        }
        #pragma unroll
        for (int mi = 0; mi < 2; ++mi)
            #pragma unroll
            for (int ni = 0; ni < 2; ++ni) {
                acc[mi][ni] = __builtin_amdgcn_mfma_f32_16x16x32_bf16(ah[mi], bh[ni], acc[mi][ni], 0, 0, 0);
                acc[mi][ni] = __builtin_amdgcn_mfma_f32_16x16x32_bf16(ah[mi], bl[ni], acc[mi][ni], 0, 0, 0);
                acc[mi][ni] = __builtin_amdgcn_mfma_f32_16x16x32_bf16(al[mi], bh[ni], acc[mi][ni], 0, 0, 0);
            }
        __syncthreads();
    }

    const int r0 = bm + wr * 32 + (lane >> 4) * 4;
    const int c0 = bn + wc * 32 + (lane & 15);
    #pragma unroll
    for (int ni = 0; ni < 2; ++ni) {
        const float bia = bias[c0 + ni * 16];
        #pragma unroll
        for (int mi = 0; mi < 2; ++mi)
            #pragma unroll
            for (int q = 0; q < 4; ++q)
                out[(size_t)(r0 + mi * 16 + q) * HID + c0 + ni * 16] = acc[mi][ni][q] + bia;
    }
}

// ============ K2: fused attention (MFMA QK^T, VALU PV) ============
__global__ __launch_bounds__(256) void attn_fused(
    const float* __restrict__ Q0,
    const float* __restrict__ K0,
    const float* __restrict__ V0,
    const float* __restrict__ rel,
    const uint4* __restrict__ cnt,
    const int* __restrict__ mask,
    float* __restrict__ out)
{
    const int x = blockIdx.x;
    const int it = x & 15;
    const int h  = (x >> 4) & 7;
    const int b  = x >> 7;
    const int i0 = it * IT;
    const int t = threadIdx.x, wave = t >> 6, lane = t & 63;

    __shared__ ushort qhi[16][72];
    __shared__ ushort qlo[16][72];
    __shared__ float qre_s[IT][8];
    __shared__ float s_t[SS][20];
    __shared__ float vtile[64][68];

    // ---- phase 0a: qrow = Q0 + sum_e cntdiag[e]*rel[e]; cvt to bf16 hi/lo ----
    const int pi = t >> 4, pd = t & 15;
    float4 qr4;
    {
        const float4 q4 = *(const float4*)&Q0[((size_t)(b * SS + i0 + pi)) * HID + h * DD + pd * 4];
        const uint4 cv = cnt[((size_t)(b * SS + i0 + pi)) * SS + (i0 + pi)];
        float c[8];
        c[0] = (float)(cv.x & 0xffff); c[1] = (float)(cv.x >> 16);
        c[2] = (float)(cv.y & 0xffff); c[3] = (float)(cv.y >> 16);
        c[4] = (float)(cv.z & 0xffff); c[5] = (float)(cv.z >> 16);
        c[6] = (float)(cv.w & 0xffff); c[7] = (float)(cv.w >> 16);
        float o0 = q4.x, o1 = q4.y, o2 = q4.z, o3 = q4.w;
        #pragma unroll
        for (int e = 0; e < 8; ++e) {
            const float4 r4 = *(const float4*)&rel[e * HID + h * DD + pd * 4];
            o0 += c[e] * r4.x; o1 += c[e] * r4.y; o2 += c[e] * r4.z; o3 += c[e] * r4.w;
        }
        qr4.x = o0; qr4.y = o1; qr4.z = o2; qr4.w = o3;
        ushort4 h4, l4;
        h4.x = f2bf(o0); l4.x = f2bf(o0 - bf2f(h4.x));
        h4.y = f2bf(o1); l4.y = f2bf(o1 - bf2f(h4.y));
        h4.z = f2bf(o2); l4.z = f2bf(o2 - bf2f(h4.z));
        h4.w = f2bf(o3); l4.w = f2bf(o3 - bf2f(h4.w));
        *(ushort4*)&qhi[pi][pd * 4] = h4;
        *(ushort4*)&qlo[pi][pd * 4] = l4;
    }
    // ---- phase 0b: qre[i][e] via shfl-reduce over pd ----
    {
        float r[8];
        #pragma unroll
        for (int e = 0; e < 8; ++e) {
            const float4 rr = *(const float4*)&rel[e * HID + h * DD + pd * 4];
            r[e] = qr4.x * rr.x + qr4.y * rr.y + qr4.z * rr.z + qr4.w * rr.w;
        }
        #pragma unroll
        for (int e = 0; e < 8; ++e) {
            float v = r[e];
            v += __shfl_xor(v, 1);
            v += __shfl_xor(v, 2);
            v += __shfl_xor(v, 4);
            v += __shfl_xor(v, 8);
            r[e] = v;
        }
        float sel = 0.f;
        #pragma unroll
        for (int e = 0; e < 8; ++e) if (pd == e) sel = r[e];
        if (pd < 8) qre_s[pi][pd] = sel;
    }
    __syncthreads();

    // ---- phase 2: scores via MFMA (3-term bf16 split); wave = jt, K from global ----
    {
        const int fr = lane & 15, kb8 = (lane >> 4) * 8;
        const int jt = wave;
        const int ib = (lane >> 4) * 4;

        short8v qh[2], ql[2];
        #pragma unroll
        for (int ks = 0; ks < 2; ++ks) {
            qh[ks] = *(const short8v*)&qhi[fr][ks * 32 + kb8];
            ql[ks] = *(const short8v*)&qlo[fr][ks * 32 + kb8];
        }
        float4 qa[4], qb[4];
        #pragma unroll
        for (int q = 0; q < 4; ++q) {
            qa[q] = *(const float4*)&qre_s[ib + q][0];
            qb[q] = *(const float4*)&qre_s[ib + q][4];
        }

        #pragma unroll
        for (int jf = 0; jf < 4; ++jf) {
            const int j = jt * 64 + jf * 16 + fr;
            const float* Kr = &K0[((size_t)(b * SS + j)) * HID + h * DD];
            f32x4 acc = {};
            #pragma unroll
            for (int ks = 0; ks < 2; ++ks) {
                const float4 k0v = *(const float4*)&Kr[ks * 32 + kb8];
                const float4 k1v = *(const float4*)&Kr[ks * 32 + kb8 + 4];
                short8v kh, kl;
                cvt8(k0v, k1v, kh, kl);
                acc = __builtin_amdgcn_mfma_f32_16x16x32_bf16(qh[ks], kh, acc, 0, 0, 0);
                acc = __builtin_amdgcn_mfma_f32_16x16x32_bf16(qh[ks], kl, acc, 0, 0, 0);
                acc = __builtin_amdgcn_mfma_f32_16x16x32_bf16(ql[ks], kh, acc, 0, 0, 0);
            }
            float sv[4];
            #pragma unroll
            for (int q = 0; q < 4; ++q) {
                const int i = ib + q;
                const uint4 cv = cnt[((size_t)(b * SS + i0 + i)) * SS + j];
                float s = acc[q]
                    + qa[q].x * (float)(cv.x & 0xffff) + qa[q].y * (float)(cv.x >> 16)
                    + qa[q].z * (float)(cv.y & 0xffff) + qa[q].w * (float)(cv.y >> 16)
                    + qb[q].x * (float)(cv.z & 0xffff) + qb[q].y * (float)(cv.z >> 16)
                    + qb[q].z * (float)(cv.w & 0xffff) + qb[q].w * (float)(cv.w >> 16);
                s *= 0.125f;
                const int m = mask[((size_t)(b * SS + i0 + i)) * SS + j];
                sv[q] = m ? s : -1e9f;
            }
            float4 w4; w4.x = sv[0]; w4.y = sv[1]; w4.z = sv[2]; w4.w = sv[3];
            *(float4*)&s_t[j][ib] = w4;
        }
    }
    __syncthreads();

    // ---- phase 3: softmax per row; wave w handles rows w*4..w*4+3 ----
    {
        #pragma unroll
        for (int rr = 0; rr < 4; ++rr) {
            const int i = wave * 4 + rr;
            float v0 = s_t[lane][i], v1 = s_t[lane + 64][i],
                  v2 = s_t[lane + 128][i], v3 = s_t[lane + 192][i];
            float mx = fmaxf(fmaxf(v0, v1), fmaxf(v2, v3));
            #pragma unroll
            for (int off = 32; off > 0; off >>= 1) mx = fmaxf(mx, __shfl_xor(mx, off));
            float e0 = __expf(v0 - mx), e1 = __expf(v1 - mx),
                  e2 = __expf(v2 - mx), e3 = __expf(v3 - mx);
            float sm = e0 + e1 + e2 + e3;
            #pragma unroll
            for (int off = 32; off > 0; off >>= 1) sm += __shfl_xor(sm, off);
            const float inv = 1.f / sm;
            s_t[lane][i] = e0 * inv;
            s_t[lane + 64][i] = e1 * inv;
            s_t[lane + 128][i] = e2 * inv;
            s_t[lane + 192][i] = e3 * inv;
        }
    }
    __syncthreads();

    // ---- phase 4: PV outer-product; thread = (iq=wave, jsub, dq) ----
    {
        const int iq = wave;
        const int jsub = (t >> 4) & 3, dq = t & 15;
        float o[4][4] = {};
        for (int jt = 0; jt < 4; ++jt) {
            {
                const int jr = t >> 2, seg = t & 3;
                const float* src = &V0[((size_t)(b * SS + jt * 64 + jr)) * HID + h * DD + seg * 16];
                #pragma unroll
                for (int qq = 0; qq < 4; ++qq)
                    *(float4*)&vtile[jr][seg * 16 + qq * 4] = *(const float4*)&src[qq * 4];
            }
            __syncthreads();
            #pragma unroll
            for (int jj = 0; jj < 16; ++jj) {
                const int j = jsub * 16 + jj;
                const float4 p4 = *(const float4*)&s_t[jt * 64 + j][iq * 4];
                const float4 v4 = *(const float4*)&vtile[j][dq * 4];
                o[0][0] += p4.x * v4.x; o[0][1] += p4.x * v4.y;
                o[0][2] += p4.x * v4.z; o[0][3] += p4.x * v4.w;
                o[1][0] += p4.y * v4.x; o[1][1] += p4.y * v4.y;
                o[1][2] += p4.y * v4.z; o[1][3] += p4.y * v4.w;
                o[2][0] += p4.z * v4.x; o[2][1] += p4.z * v4.y;
                o[2][2] += p4.z * v4.z; o[2][3] += p4.z * v4.w;
                o[3][0] += p4.w * v4.x; o[3][1] += p4.w * v4.y;
                o[3][2] += p4.w * v4.z; o[3][3] += p4.w * v4.w;
            }
            __syncthreads();
        }
        #pragma unroll
        for (int r = 0; r < 4; ++r)
            #pragma unroll
            for (int c = 0; c < 4; ++c) {
                float v = o[r][c];
                v += __shfl_xor(v, 16);
                v += __shfl_xor(v, 32);
                o[r][c] = v;
            }
        float sel0 = 0.f, sel1 = 0.f, sel2 = 0.f, sel3 = 0.f;
        #pragma unroll
        for (int r = 0; r < 4; ++r)
            if (r == jsub) { sel0 = o[r][0]; sel1 = o[r][1]; sel2 = o[r][2]; sel3 = o[r][3]; }
        const int i = iq * 4 + jsub;
        float4 ov; ov.x = sel0; ov.y = sel1; ov.z = sel2; ov.w = sel3;
        *(float4*)&out[((size_t)(b * SS + i0 + i)) * HID + h * DD + dq * 4] = ov;
    }
}

extern "C" void kernel_launch(void* const* d_in, const int* in_sizes, int n_in,
                              void* d_out, int out_size, void* d_ws, size_t ws_size,
                              hipStream_t stream) {
    const float* q_hs = (const float*)d_in[0];
    const float* k_hs = (const float*)d_in[1];
    const float* v_hs = (const float*)d_in[2];
    const float* Wq   = (const float*)d_in[3];
    const float* bq   = (const float*)d_in[4];
    const float* Wk   = (const float*)d_in[5];
    const float* bk   = (const float*)d_in[6];
    const float* Wv   = (const float*)d_in[7];
    const float* bv   = (const float*)d_in[8];
    const float* rel  = (const float*)d_in[9];
    const int* edge   = (const int*)d_in[10];
    const int* mask   = (const int*)d_in[11];
    float* out = (float*)d_out;

    char* ws = (char*)d_ws;
    float*  Q    = (float*)(ws);                         // 2 MB [B,S,HID]
    float*  K0   = (float*)(ws + (2u  << 20));           // 2 MB
    float*  V0   = (float*)(ws + (4u  << 20));           // 2 MB
    uint4*  cnt  = (uint4*)(ws + (6u  << 20));           // 4 MB

    gemm_cnt<<<dim3(640), 256, 0, stream>>>(q_hs, k_hs, v_hs, Wq, Wk, Wv,
                                            bq, bk, bv, Q, K0, V0, edge, cnt);
    attn_fused<<<dim3(BB * NHD * (SS / IT)), 256, 0, stream>>>(Q, K0, V0, rel, cnt, mask, out);
}

// Round 11
// 110.508 us; speedup vs baseline: 2.3446x; 1.0235x over previous
//
#include <hip/hip_runtime.h>
#include <math.h>

#define BB 4
#define SS 256
#define HID 512
#define NHD 8
#define DD 64
#define IT 16

typedef __attribute__((ext_vector_type(8))) short short8v;   // 8 bf16
typedef __attribute__((ext_vector_type(4))) float f32x4;

static __device__ __forceinline__ ushort f2bf(float x) {
    uint u = __float_as_uint(x);
    uint r = u + 0x7fffu + ((u >> 16) & 1u);   // RNE
    return (ushort)(r >> 16);
}
static __device__ __forceinline__ float bf2f(ushort h) {
    return __uint_as_float(((uint)h) << 16);
}
static __device__ __forceinline__ void cvt8(const float4& a, const float4& b,
                                            short8v& hi, short8v& lo) {
    ushort h;
    h = f2bf(a.x); hi[0] = (short)h; lo[0] = (short)f2bf(a.x - bf2f(h));
    h = f2bf(a.y); hi[1] = (short)h; lo[1] = (short)f2bf(a.y - bf2f(h));
    h = f2bf(a.z); hi[2] = (short)h; lo[2] = (short)f2bf(a.z - bf2f(h));
    h = f2bf(a.w); hi[3] = (short)h; lo[3] = (short)f2bf(a.w - bf2f(h));
    h = f2bf(b.x); hi[4] = (short)h; lo[4] = (short)f2bf(b.x - bf2f(h));
    h = f2bf(b.y); hi[5] = (short)h; lo[5] = (short)f2bf(b.y - bf2f(h));
    h = f2bf(b.z); hi[6] = (short)h; lo[6] = (short)f2bf(b.z - bf2f(h));
    h = f2bf(b.w); hi[7] = (short)h; lo[7] = (short)f2bf(b.w - bf2f(h));
}

// ============ K1: blocks 0-383 = QKV GEMM | 384-639 = cnt scan ============
// z=0 -> Q fp32 [B,S,HID]; z=1 -> K bf16 hi/lo [B,S,HID]; z=2 -> V^T bf16 hi/lo [B,H,D,S]
__global__ __launch_bounds__(256) void gemm_cnt(
    const float* __restrict__ xq, const float* __restrict__ xk, const float* __restrict__ xv,
    const float* __restrict__ wq, const float* __restrict__ wk, const float* __restrict__ wv,
    const float* __restrict__ bq, const float* __restrict__ bk, const float* __restrict__ bv,
    float* __restrict__ Qo, ushort* __restrict__ Khi, ushort* __restrict__ Klo,
    ushort* __restrict__ Vthi, ushort* __restrict__ Vtlo,
    const int* __restrict__ edge, uint4* __restrict__ cnt)
{
    const int bid = blockIdx.x;
    const int t = threadIdx.x;
    const int wave = t >> 6, lane = t & 63;

    if (bid >= 384) {
        // ---- cumulative histogram: one wave per column (b,j), packed 8 x u16 ----
        const int col = (bid - 384) * 4 + wave;
        const int b = col / SS, j = col % SS;
        uint4 run = make_uint4(0, 0, 0, 0);
        uint4 c[4];
        #pragma unroll
        for (int r = 0; r < 4; ++r) {
            const int e = edge[((size_t)(b * SS + lane * 4 + r)) * SS + j];
            const unsigned inc = 1u << ((e & 1) * 16);
            const int comp = e >> 1;
            run.x += (comp == 0) ? inc : 0u;
            run.y += (comp == 1) ? inc : 0u;
            run.z += (comp == 2) ? inc : 0u;
            run.w += (comp == 3) ? inc : 0u;
            c[r] = run;
        }
        uint4 tot = run;
        #pragma unroll
        for (int off = 1; off < 64; off <<= 1) {
            uint4 s;
            s.x = __shfl_up((int)tot.x, off);
            s.y = __shfl_up((int)tot.y, off);
            s.z = __shfl_up((int)tot.z, off);
            s.w = __shfl_up((int)tot.w, off);
            if (lane >= off) { tot.x += s.x; tot.y += s.y; tot.z += s.z; tot.w += s.w; }
        }
        const uint4 excl = make_uint4(tot.x - run.x, tot.y - run.y, tot.z - run.z, tot.w - run.w);
        #pragma unroll
        for (int r = 0; r < 4; ++r) {
            uint4 o = make_uint4(excl.x + c[r].x, excl.y + c[r].y, excl.z + c[r].z, excl.w + c[r].w);
            cnt[((size_t)(b * SS + lane * 4 + r)) * SS + j] = o;
        }
        return;
    }

    // ---- GEMM: 64x64 tile, BK=32, bf16-split MFMA ----
    __shared__ ushort As_hi[64][40];
    __shared__ ushort As_lo[64][40];
    __shared__ ushort Bs_hi[64][40];
    __shared__ ushort Bs_lo[64][40];

    const int z = bid / 128, rr = bid % 128;
    const float* X    = (z == 0) ? xq : (z == 1) ? xk : xv;
    const float* W    = (z == 0) ? wq : (z == 1) ? wk : wv;
    const float* bias = (z == 0) ? bq : (z == 1) ? bk : bv;
    const int bm = (rr & 15) * 64, bn = (rr >> 4) * 64;

    const int wr = wave >> 1, wc = wave & 1;
    const int sm = t >> 2, sk = (t & 3) * 8;       // X staging: row, k-chunk
    const int wn = t & 63, wks = (t >> 6) * 8;     // W staging: col n, k-chunk
    const int fr = lane & 15, kb = (lane >> 4) * 8;

    f32x4 acc[2][2] = {};

    for (int k0 = 0; k0 < HID; k0 += 32) {
        {
            const float* xp = &X[(size_t)(bm + sm) * HID + k0 + sk];
            const float4 a0 = *(const float4*)&xp[0];
            const float4 a1 = *(const float4*)&xp[4];
            short8v h8, l8;
            cvt8(a0, a1, h8, l8);
            *(short8v*)&As_hi[sm][sk] = h8;
            *(short8v*)&As_lo[sm][sk] = l8;
        }
        {
            float wv8[8];
            #pragma unroll
            for (int j = 0; j < 8; ++j)
                wv8[j] = W[(size_t)(k0 + wks + j) * HID + bn + wn];
            short8v wh, wl;
            #pragma unroll
            for (int j = 0; j < 8; ++j) {
                const ushort h = f2bf(wv8[j]);
                wh[j] = (short)h;
                wl[j] = (short)f2bf(wv8[j] - bf2f(h));
            }
            *(short8v*)&Bs_hi[wn][wks] = wh;
            *(short8v*)&Bs_lo[wn][wks] = wl;
        }
        __syncthreads();

        short8v ah[2], al[2], bh[2], bl[2];
        #pragma unroll
        for (int mi = 0; mi < 2; ++mi) {
            ah[mi] = *(const short8v*)&As_hi[wr * 32 + mi * 16 + fr][kb];
            al[mi] = *(const short8v*)&As_lo[wr * 32 + mi * 16 + fr][kb];
        }
        #pragma unroll
        for (int ni = 0; ni < 2; ++ni) {
            bh[ni] = *(const short8v*)&Bs_hi[wc * 32 + ni * 16 + fr][kb];
            bl[ni] = *(const short8v*)&Bs_lo[wc * 32 + ni * 16 + fr][kb];
        }
        #pragma unroll
        for (int mi = 0; mi < 2; ++mi)
            #pragma unroll
            for (int ni = 0; ni < 2; ++ni) {
                acc[mi][ni] = __builtin_amdgcn_mfma_f32_16x16x32_bf16(ah[mi], bh[ni], acc[mi][ni], 0, 0, 0);
                acc[mi][ni] = __builtin_amdgcn_mfma_f32_16x16x32_bf16(ah[mi], bl[ni], acc[mi][ni], 0, 0, 0);
                acc[mi][ni] = __builtin_amdgcn_mfma_f32_16x16x32_bf16(al[mi], bh[ni], acc[mi][ni], 0, 0, 0);
            }
        __syncthreads();
    }

    // epilogue: D row = (lane>>4)*4+q, col = lane&15 (within 16-frag)
    const int r0 = bm + wr * 32 + (lane >> 4) * 4;
    const int c0 = bn + wc * 32 + (lane & 15);
    if (z == 0) {
        #pragma unroll
        for (int ni = 0; ni < 2; ++ni) {
            const float bia = bias[c0 + ni * 16];
            #pragma unroll
            for (int mi = 0; mi < 2; ++mi)
                #pragma unroll
                for (int q = 0; q < 4; ++q)
                    Qo[(size_t)(r0 + mi * 16 + q) * HID + c0 + ni * 16] = acc[mi][ni][q] + bia;
        }
    } else if (z == 1) {
        #pragma unroll
        for (int ni = 0; ni < 2; ++ni) {
            const float bia = bias[c0 + ni * 16];
            #pragma unroll
            for (int mi = 0; mi < 2; ++mi)
                #pragma unroll
                for (int q = 0; q < 4; ++q) {
                    const float v = acc[mi][ni][q] + bia;
                    const ushort h = f2bf(v);
                    const size_t o = (size_t)(r0 + mi * 16 + q) * HID + c0 + ni * 16;
                    Khi[o] = h;
                    Klo[o] = f2bf(v - bf2f(h));
                }
        }
    } else {
        #pragma unroll
        for (int ni = 0; ni < 2; ++ni) {
            const int c = c0 + ni * 16;
            const float bia = bias[c];
            const int hh = c >> 6, dd = c & 63;
            #pragma unroll
            for (int mi = 0; mi < 2; ++mi) {
                const int tok = r0 + mi * 16;
                const int b2 = tok / SS, s0 = tok % SS;
                ushort4 h4, l4;
                float v;
                v = acc[mi][ni][0] + bia; h4.x = f2bf(v); l4.x = f2bf(v - bf2f(h4.x));
                v = acc[mi][ni][1] + bia; h4.y = f2bf(v); l4.y = f2bf(v - bf2f(h4.y));
                v = acc[mi][ni][2] + bia; h4.z = f2bf(v); l4.z = f2bf(v - bf2f(h4.z));
                v = acc[mi][ni][3] + bia; h4.w = f2bf(v); l4.w = f2bf(v - bf2f(h4.w));
                const size_t o = (((size_t)b2 * NHD + hh) * DD + dd) * SS + s0;
                *(ushort4*)&Vthi[o] = h4;
                *(ushort4*)&Vtlo[o] = l4;
            }
        }
    }
}

// ============ K2: fused attention — MFMA QK^T and MFMA PV ============
__global__ __launch_bounds__(256) void attn_fused(
    const float* __restrict__ Q0,
    const ushort* __restrict__ Khi, const ushort* __restrict__ Klo,
    const ushort* __restrict__ Vthi, const ushort* __restrict__ Vtlo,
    const float* __restrict__ rel,
    const uint4* __restrict__ cnt,
    const int* __restrict__ mask,
    float* __restrict__ out)
{
    const int x = blockIdx.x;
    const int it = x & 15;
    const int h  = (x >> 4) & 7;
    const int b  = x >> 7;
    const int i0 = it * IT;
    const int t = threadIdx.x, wave = t >> 6, lane = t & 63;

    __shared__ ushort qhi[16][72];
    __shared__ ushort qlo[16][72];
    __shared__ float qre_s[IT][8];
    __shared__ float s_t[SS][20];       // scores [j][i] fp32
    __shared__ ushort pb_hi[16][264];   // probs bf16 [i][j]
    __shared__ ushort pb_lo[16][264];

    // ---- phase 0a: qrow = Q0 + sum_e cntdiag[e]*rel[e]; cvt to bf16 hi/lo ----
    const int pi = t >> 4, pd = t & 15;
    float4 qr4;
    {
        const float4 q4 = *(const float4*)&Q0[((size_t)(b * SS + i0 + pi)) * HID + h * DD + pd * 4];
        const uint4 cv = cnt[((size_t)(b * SS + i0 + pi)) * SS + (i0 + pi)];
        float c[8];
        c[0] = (float)(cv.x & 0xffff); c[1] = (float)(cv.x >> 16);
        c[2] = (float)(cv.y & 0xffff); c[3] = (float)(cv.y >> 16);
        c[4] = (float)(cv.z & 0xffff); c[5] = (float)(cv.z >> 16);
        c[6] = (float)(cv.w & 0xffff); c[7] = (float)(cv.w >> 16);
        float o0 = q4.x, o1 = q4.y, o2 = q4.z, o3 = q4.w;
        #pragma unroll
        for (int e = 0; e < 8; ++e) {
            const float4 r4 = *(const float4*)&rel[e * HID + h * DD + pd * 4];
            o0 += c[e] * r4.x; o1 += c[e] * r4.y; o2 += c[e] * r4.z; o3 += c[e] * r4.w;
        }
        qr4.x = o0; qr4.y = o1; qr4.z = o2; qr4.w = o3;
        ushort4 h4, l4;
        h4.x = f2bf(o0); l4.x = f2bf(o0 - bf2f(h4.x));
        h4.y = f2bf(o1); l4.y = f2bf(o1 - bf2f(h4.y));
        h4.z = f2bf(o2); l4.z = f2bf(o2 - bf2f(h4.z));
        h4.w = f2bf(o3); l4.w = f2bf(o3 - bf2f(h4.w));
        *(ushort4*)&qhi[pi][pd * 4] = h4;
        *(ushort4*)&qlo[pi][pd * 4] = l4;
    }
    // ---- phase 0b: qre[i][e] via shfl-reduce over pd ----
    {
        float r[8];
        #pragma unroll
        for (int e = 0; e < 8; ++e) {
            const float4 rr = *(const float4*)&rel[e * HID + h * DD + pd * 4];
            r[e] = qr4.x * rr.x + qr4.y * rr.y + qr4.z * rr.z + qr4.w * rr.w;
        }
        #pragma unroll
        for (int e = 0; e < 8; ++e) {
            float v = r[e];
            v += __shfl_xor(v, 1);
            v += __shfl_xor(v, 2);
            v += __shfl_xor(v, 4);
            v += __shfl_xor(v, 8);
            r[e] = v;
        }
        float sel = 0.f;
        #pragma unroll
        for (int e = 0; e < 8; ++e) if (pd == e) sel = r[e];
        if (pd < 8) qre_s[pi][pd] = sel;
    }
    __syncthreads();

    const int fr = lane & 15, kb8 = (lane >> 4) * 8;

    // ---- phase 2: scores via MFMA; wave = j-tile; K frags direct from bf16 global ----
    {
        const int jt = wave;
        const int ib = (lane >> 4) * 4;

        short8v qh[2], ql[2];
        #pragma unroll
        for (int ks = 0; ks < 2; ++ks) {
            qh[ks] = *(const short8v*)&qhi[fr][ks * 32 + kb8];
            ql[ks] = *(const short8v*)&qlo[fr][ks * 32 + kb8];
        }
        float4 qa[4], qb[4];
        #pragma unroll
        for (int q = 0; q < 4; ++q) {
            qa[q] = *(const float4*)&qre_s[ib + q][0];
            qb[q] = *(const float4*)&qre_s[ib + q][4];
        }

        #pragma unroll
        for (int jf = 0; jf < 4; ++jf) {
            const int j = jt * 64 + jf * 16 + fr;
            const size_t kbase = ((size_t)(b * SS + j)) * HID + h * DD;
            f32x4 acc = {};
            #pragma unroll
            for (int ks = 0; ks < 2; ++ks) {
                const short8v kh = *(const short8v*)&Khi[kbase + ks * 32 + kb8];
                const short8v kl = *(const short8v*)&Klo[kbase + ks * 32 + kb8];
                acc = __builtin_amdgcn_mfma_f32_16x16x32_bf16(qh[ks], kh, acc, 0, 0, 0);
                acc = __builtin_amdgcn_mfma_f32_16x16x32_bf16(qh[ks], kl, acc, 0, 0, 0);
                acc = __builtin_amdgcn_mfma_f32_16x16x32_bf16(ql[ks], kh, acc, 0, 0, 0);
            }
            float sv[4];
            #pragma unroll
            for (int q = 0; q < 4; ++q) {
                const int i = ib + q;
                const uint4 cv = cnt[((size_t)(b * SS + i0 + i)) * SS + j];
                float s = acc[q]
                    + qa[q].x * (float)(cv.x & 0xffff) + qa[q].y * (float)(cv.x >> 16)
                    + qa[q].z * (float)(cv.y & 0xffff) + qa[q].w * (float)(cv.y >> 16)
                    + qb[q].x * (float)(cv.z & 0xffff) + qb[q].y * (float)(cv.z >> 16)
                    + qb[q].z * (float)(cv.w & 0xffff) + qb[q].w * (float)(cv.w >> 16);
                s *= 0.125f;
                const int m = mask[((size_t)(b * SS + i0 + i)) * SS + j];
                sv[q] = m ? s : -1e9f;
            }
            float4 w4; w4.x = sv[0]; w4.y = sv[1]; w4.z = sv[2]; w4.w = sv[3];
            *(float4*)&s_t[j][ib] = w4;
        }
    }
    __syncthreads();

    // ---- phase 3: softmax per row; write probs to pb as bf16 hi/lo [i][j] ----
    {
        #pragma unroll
        for (int rr = 0; rr < 4; ++rr) {
            const int i = wave * 4 + rr;
            float v0 = s_t[lane][i], v1 = s_t[lane + 64][i],
                  v2 = s_t[lane + 128][i], v3 = s_t[lane + 192][i];
            float mx = fmaxf(fmaxf(v0, v1), fmaxf(v2, v3));
            #pragma unroll
            for (int off = 32; off > 0; off >>= 1) mx = fmaxf(mx, __shfl_xor(mx, off));
            float e0 = __expf(v0 - mx), e1 = __expf(v1 - mx),
                  e2 = __expf(v2 - mx), e3 = __expf(v3 - mx);
            float sm = e0 + e1 + e2 + e3;
            #pragma unroll
            for (int off = 32; off > 0; off >>= 1) sm += __shfl_xor(sm, off);
            const float inv = 1.f / sm;
            e0 *= inv; e1 *= inv; e2 *= inv; e3 *= inv;
            ushort h;
            h = f2bf(e0); pb_hi[i][lane      ] = h; pb_lo[i][lane      ] = f2bf(e0 - bf2f(h));
            h = f2bf(e1); pb_hi[i][lane +  64] = h; pb_lo[i][lane +  64] = f2bf(e1 - bf2f(h));
            h = f2bf(e2); pb_hi[i][lane + 128] = h; pb_lo[i][lane + 128] = f2bf(e2 - bf2f(h));
            h = f2bf(e3); pb_hi[i][lane + 192] = h; pb_lo[i][lane + 192] = f2bf(e3 - bf2f(h));
        }
    }
    __syncthreads();

    // ---- phase 4: PV via MFMA; wave = d-quadrant; V^T frags direct from bf16 global ----
    {
        const int dcol = wave * 16 + fr;
        const size_t vbase = (((size_t)b * NHD + h) * DD + dcol) * SS;
        f32x4 opv = {};
        #pragma unroll
        for (int jt = 0; jt < 4; ++jt)
            #pragma unroll
            for (int c2 = 0; c2 < 2; ++c2) {
                const int joff = jt * 64 + c2 * 32 + kb8;
                const short8v ph = *(const short8v*)&pb_hi[fr][joff];
                const short8v pl = *(const short8v*)&pb_lo[fr][joff];
                const short8v vh = *(const short8v*)&Vthi[vbase + joff];
                const short8v vl = *(const short8v*)&Vtlo[vbase + joff];
                opv = __builtin_amdgcn_mfma_f32_16x16x32_bf16(ph, vh, opv, 0, 0, 0);
                opv = __builtin_amdgcn_mfma_f32_16x16x32_bf16(pl, vh, opv, 0, 0, 0);
                opv = __builtin_amdgcn_mfma_f32_16x16x32_bf16(ph, vl, opv, 0, 0, 0);
            }
        #pragma unroll
        for (int q = 0; q < 4; ++q) {
            const int i = (lane >> 4) * 4 + q;
            out[((size_t)(b * SS + i0 + i)) * HID + h * DD + dcol] = opv[q];
        }
    }
}

extern "C" void kernel_launch(void* const* d_in, const int* in_sizes, int n_in,
                              void* d_out, int out_size, void* d_ws, size_t ws_size,
                              hipStream_t stream) {
    const float* q_hs = (const float*)d_in[0];
    const float* k_hs = (const float*)d_in[1];
    const float* v_hs = (const float*)d_in[2];
    const float* Wq   = (const float*)d_in[3];
    const float* bq   = (const float*)d_in[4];
    const float* Wk   = (const float*)d_in[5];
    const float* bk   = (const float*)d_in[6];
    const float* Wv   = (const float*)d_in[7];
    const float* bv   = (const float*)d_in[8];
    const float* rel  = (const float*)d_in[9];
    const int* edge   = (const int*)d_in[10];
    const int* mask   = (const int*)d_in[11];
    float* out = (float*)d_out;

    char* ws = (char*)d_ws;
    float*  Q    = (float*)(ws);                 // 2 MB [B,S,HID] fp32
    ushort* Khi  = (ushort*)(ws + (2u << 20));   // 1 MB [B,S,HID] bf16
    ushort* Klo  = (ushort*)(ws + (3u << 20));   // 1 MB
    ushort* Vthi = (ushort*)(ws + (4u << 20));   // 1 MB [B,H,D,S] bf16
    ushort* Vtlo = (ushort*)(ws + (5u << 20));   // 1 MB
    uint4*  cnt  = (uint4*)(ws + (6u << 20));    // 4 MB

    gemm_cnt<<<dim3(640), 256, 0, stream>>>(q_hs, k_hs, v_hs, Wq, Wk, Wv,
                                            bq, bk, bv, Q, Khi, Klo, Vthi, Vtlo,
                                            edge, cnt);
    attn_fused<<<dim3(BB * NHD * (SS / IT)), 256, 0, stream>>>(Q, Khi, Klo, Vthi, Vtlo,
                                                               rel, cnt, mask, out);
}